// Round 3
// baseline (438.227 us; speedup 1.0000x reference)
//
#include <hip/hip_runtime.h>
#include <hip/hip_bf16.h>
#include <math.h>

#define TID ((int)threadIdx.x)

typedef float f32x4 __attribute__((ext_vector_type(4)));
typedef short s16x8 __attribute__((ext_vector_type(8)));

__device__ __forceinline__ unsigned short f2bf(float f) {
  union { float f; unsigned u; } v; v.f = f;
  unsigned r = v.u + 0x7FFFu + ((v.u >> 16) & 1u);
  return (unsigned short)(r >> 16);
}
__device__ __forceinline__ float bf2f(unsigned short h) {
  union { unsigned u; float f; } v; v.u = ((unsigned)h) << 16;
  return v.f;
}

#define BAR_LGKM() do { asm volatile("s_waitcnt lgkmcnt(0)" ::: "memory"); \
                        __builtin_amdgcn_s_barrier(); } while (0)

// ---------------- prep: weight transpose->bf16 + RoPE trig table ----------------
__global__ void prep_kernel(const float* __restrict__ eeg_w,
                            const float* __restrict__ k_w,
                            const float* __restrict__ v_w,
                            unsigned short* __restrict__ wt,
                            float2* __restrict__ trig) {
  int gid = blockIdx.x * 256 + TID;            // grid = 1024*256 = 262144 exactly
  if (gid < 3 * 65536) {
    int m = gid >> 16, e = gid & 65535;
    int i = e >> 8, j = e & 255;
    const float* W = (m == 0) ? eeg_w : ((m == 1) ? k_w : v_w);
    wt[m * 65536 + j * 256 + i] = f2bf(W[i * 256 + j]);
  } else {
    int e = gid - 3 * 65536;
    int n = e >> 4, p = e & 15;
    float inv = exp2f(-(float)p * 0.8304820237218406f);  // 10000^(-p/16)
    float a = (float)n * inv;
    trig[e] = make_float2(cosf(a), sinf(a));
  }
}

// ---------------- query path (unchanged, verified) ----------------
__global__ __launch_bounds__(256) void q_kernel(
    const float* __restrict__ stim_feat, const float* __restrict__ temp_feat,
    const float* __restrict__ stim_w, const float* __restrict__ stim_b,
    const float* __restrict__ temp_w, const float* __restrict__ temp_b,
    const float* __restrict__ q_w, const float* __restrict__ q_b,
    const float* __restrict__ lnq_g, const float* __restrict__ lnq_b,
    float* __restrict__ out_query, float* __restrict__ qhat) {
  int b = blockIdx.x >> 1, q = blockIdx.x & 1;
  __shared__ float f[256];
  __shared__ float red[8];
  const float* feat = (q ? temp_feat : stim_feat) + b * 256;
  const float* W = q ? temp_w : stim_w;
  const float* bias = q ? temp_b : stim_b;
  f[TID] = feat[TID];
  __syncthreads();
  float acc = bias[TID];
#pragma unroll 8
  for (int i = 0; i < 256; ++i) acc = fmaf(f[i], W[i * 256 + TID], acc);
  float s1 = acc, s2 = acc * acc;
#pragma unroll
  for (int m = 1; m < 64; m <<= 1) { s1 += __shfl_xor(s1, m, 64); s2 += __shfl_xor(s2, m, 64); }
  if ((TID & 63) == 0) { red[TID >> 6] = s1; red[4 + (TID >> 6)] = s2; }
  __syncthreads();
  s1 = red[0] + red[1] + red[2] + red[3];
  s2 = red[4] + red[5] + red[6] + red[7];
  float mean = s1 * (1.f / 256.f);
  float var = s2 * (1.f / 256.f) - mean * mean;
  float rstd = rsqrtf(var + 1e-5f);
  float qln = (acc - mean) * rstd * lnq_g[TID] + lnq_b[TID];
  out_query[(b * 2 + q) * 256 + TID] = qln;
  __syncthreads();
  f[TID] = qln;
  __syncthreads();
  float a2 = q_b[TID];
#pragma unroll 8
  for (int i = 0; i < 256; ++i) a2 = fmaf(f[i], q_w[i * 256 + TID], a2);
  __syncthreads();
  f[TID] = a2;
  __syncthreads();
  float partner = f[TID ^ 1];
  int p = (TID >> 1) & 15;
  float inv = exp2f(-(float)p * 0.8304820237218406f);
  float ang = (float)q * inv;
  float cc_ = cosf(ang), ss_ = sinf(ang);
  float r = (TID & 1) ? fmaf(a2, cc_, partner * ss_) : fmaf(a2, cc_, -partner * ss_);
  float sq = r * r;
#pragma unroll
  for (int m = 1; m < 32; m <<= 1) sq += __shfl_xor(sq, m, 32);
  float rs = 1.f / fmaxf(sqrtf(sq), 1e-12f);
  qhat[(b * 2 + q) * 256 + TID] = r * rs;
}

// ---------------- kA: eeg proj (weight-stationary) + LN -> xp (swizzled bf16) ----------------
__global__ __launch_bounds__(256, 2) void eeg_ln_kernel(
    const float* __restrict__ x,
    const float* __restrict__ eeg_b,
    const float* __restrict__ lnk_g,
    const float* __restrict__ lnk_b,
    const unsigned short* __restrict__ wt_eeg,
    unsigned short* __restrict__ xp) {

  __shared__ __align__(16) unsigned short A[64 * 256];  // 32KB swizzled tile
  __shared__ float PS[64 * 8];
  __shared__ float2 ST[64];

  const int tid = TID;
  const int w = tid >> 6, l = tid & 63, g = l >> 4, c = l & 15;
  const int r0 = blockIdx.x * 64;

  // ---- B half0 loads (cb 0,1) issue first: overlap with X staging ----
  s16x8 bA[8][2];
#pragma unroll
  for (int ks = 0; ks < 8; ++ks)
#pragma unroll
    for (int j = 0; j < 2; ++j)
      bA[ks][j] = *(const s16x8*)&wt_eeg[(size_t)(w * 64 + j * 16 + c) * 256 + ks * 32 + g * 8];

  // ---- stage X (fp32 -> bf16, swizzled) ----
#pragma unroll
  for (int i = 0; i < 8; ++i) {
    int ch = i * 256 + tid;
    int row = ch >> 5, cc = ch & 31;
    const float4* gp = (const float4*)(x + (size_t)(r0 + row) * 256 + cc * 8);
    float4 u0 = gp[0], u1 = gp[1];
    s16x8 pk;
    pk[0] = (short)f2bf(u0.x); pk[1] = (short)f2bf(u0.y);
    pk[2] = (short)f2bf(u0.z); pk[3] = (short)f2bf(u0.w);
    pk[4] = (short)f2bf(u1.x); pk[5] = (short)f2bf(u1.y);
    pk[6] = (short)f2bf(u1.z); pk[7] = (short)f2bf(u1.w);
    *(s16x8*)&A[row * 256 + ((cc ^ (row & 7)) * 8)] = pk;
  }

  float ebias[4], gg[4], bb[4];
  int cols[4];
#pragma unroll
  for (int cb = 0; cb < 4; ++cb) {
    int col = w * 64 + cb * 16 + c;
    cols[cb] = col;
    ebias[cb] = eeg_b[col]; gg[cb] = lnk_g[col]; bb[cb] = lnk_b[col];
  }
  __syncthreads();

  f32x4 acc[4][4];
#pragma unroll
  for (int rb = 0; rb < 4; ++rb)
#pragma unroll
    for (int cb = 0; cb < 4; ++cb) acc[rb][cb] = (f32x4){0.f, 0.f, 0.f, 0.f};

  // ---- GEMM half0 (cb 0,1) ----
#pragma unroll
  for (int ks = 0; ks < 8; ++ks) {
    s16x8 af[4];
#pragma unroll
    for (int rb = 0; rb < 4; ++rb) {
      int row = rb * 16 + c; int kc = ks * 4 + g;
      af[rb] = *(const s16x8*)&A[row * 256 + ((kc ^ (row & 7)) * 8)];
    }
#pragma unroll
    for (int rb = 0; rb < 4; ++rb)
#pragma unroll
      for (int j = 0; j < 2; ++j)
        acc[rb][j] = __builtin_amdgcn_mfma_f32_16x16x32_bf16(af[rb], bA[ks][j], acc[rb][j], 0, 0, 0);
  }
  // ---- B half1 loads + GEMM half1 (cb 2,3) ----
  s16x8 bB[8][2];
#pragma unroll
  for (int ks = 0; ks < 8; ++ks)
#pragma unroll
    for (int j = 0; j < 2; ++j)
      bB[ks][j] = *(const s16x8*)&wt_eeg[(size_t)(w * 64 + (2 + j) * 16 + c) * 256 + ks * 32 + g * 8];
#pragma unroll
  for (int ks = 0; ks < 8; ++ks) {
    s16x8 af[4];
#pragma unroll
    for (int rb = 0; rb < 4; ++rb) {
      int row = rb * 16 + c; int kc = ks * 4 + g;
      af[rb] = *(const s16x8*)&A[row * 256 + ((kc ^ (row & 7)) * 8)];
    }
#pragma unroll
    for (int rb = 0; rb < 4; ++rb)
#pragma unroll
      for (int j = 0; j < 2; ++j)
        acc[rb][2 + j] = __builtin_amdgcn_mfma_f32_16x16x32_bf16(af[rb], bB[ks][j], acc[rb][2 + j], 0, 0, 0);
  }

  // ---- LN stats ----
  {
    float ps[4][4], pq[4][4];
#pragma unroll
    for (int rb = 0; rb < 4; ++rb)
#pragma unroll
      for (int r = 0; r < 4; ++r) {
        float s = 0.f, q2 = 0.f;
#pragma unroll
        for (int cb = 0; cb < 4; ++cb) {
          float v = acc[rb][cb][r] + ebias[cb];
          s += v; q2 += v * v;
        }
        ps[rb][r] = s; pq[rb][r] = q2;
      }
#pragma unroll
    for (int m = 1; m < 16; m <<= 1)
#pragma unroll
      for (int rb = 0; rb < 4; ++rb)
#pragma unroll
        for (int r = 0; r < 4; ++r) {
          ps[rb][r] += __shfl_xor(ps[rb][r], m, 64);
          pq[rb][r] += __shfl_xor(pq[rb][r], m, 64);
        }
    float outS = 0.f, outQ = 0.f;
#pragma unroll
    for (int rb = 0; rb < 4; ++rb)
#pragma unroll
      for (int r = 0; r < 4; ++r)
        if (c == rb * 4 + r) { outS = ps[rb][r]; outQ = pq[rb][r]; }
    int row = (c >> 2) * 16 + g * 4 + (c & 3);
    PS[row * 8 + w * 2 + 0] = outS;
    PS[row * 8 + w * 2 + 1] = outQ;
  }
  __syncthreads();
  if (tid < 64) {
    float s = PS[tid * 8 + 0] + PS[tid * 8 + 2] + PS[tid * 8 + 4] + PS[tid * 8 + 6];
    float q2 = PS[tid * 8 + 1] + PS[tid * 8 + 3] + PS[tid * 8 + 5] + PS[tid * 8 + 7];
    float mean = s * (1.f / 256.f);
    float var = q2 * (1.f / 256.f) - mean * mean;
    ST[tid] = make_float2(mean, rsqrtf(var + 1e-5f));
  }
  __syncthreads();

  // ---- LN apply -> A (swizzled, in place) ----
#pragma unroll
  for (int rb = 0; rb < 4; ++rb)
#pragma unroll
    for (int r = 0; r < 4; ++r) {
      int row = rb * 16 + g * 4 + r;
      float2 st = ST[row];
#pragma unroll
      for (int cb = 0; cb < 4; ++cb) {
        float v = (acc[rb][cb][r] + ebias[cb] - st.x) * st.y * gg[cb] + bb[cb];
        A[row * 256 + (cols[cb] ^ ((row & 7) * 8))] = f2bf(v);
      }
    }
  __syncthreads();

  // ---- dump swizzled tile linearly to xp (coalesced b128) ----
#pragma unroll
  for (int j = 0; j < 8; ++j) {
    int gidx = tid + 256 * j;
    *(s16x8*)&xp[(size_t)r0 * 256 + (size_t)gidx * 8] = *(const s16x8*)&A[gidx * 8];
  }
}

// ---------------- kB: K proj (+RoPE -> scores) & V proj (-> vws), 8 waves, 4 tiles ----------------
__global__ __launch_bounds__(512, 2) void kv_kernel(
    const unsigned short* __restrict__ xp,
    const float* __restrict__ k_b,
    const float* __restrict__ v_b,
    const unsigned short* __restrict__ wt_k,
    const unsigned short* __restrict__ wt_v,
    const float2* __restrict__ trig,
    const float* __restrict__ qhat,
    float* __restrict__ scores,
    unsigned short* __restrict__ vws) {

  __shared__ __align__(16) unsigned short A[64 * 256];   // staged (swizzled) X' tile / later V (plain)
  __shared__ __align__(16) unsigned short K2[64 * 256];  // RoPE'd K (swizzled)
  __shared__ __align__(16) float2 TR[1024];              // trig rows for current tile
  __shared__ float QH[512];                              // qhat q0|q1 for this b

  const int tid = TID;
  const int w8 = tid >> 6, l = tid & 63, g = l >> 4, c = l & 15;
  const int kv = w8 >> 2;          // 0 = K waves, 1 = V waves
  const int w = w8 & 3;            // col-group within role
  const int blkrow0 = blockIdx.x * 256;   // 4 tiles of 64 rows
  const int b = blkrow0 >> 12;

  const unsigned short* wsel = kv ? wt_v : wt_k;
  const float* bsel = kv ? v_b : k_b;

  float bias[4];
  int cols[4];
#pragma unroll
  for (int cb = 0; cb < 4; ++cb) {
    int col = w * 64 + cb * 16 + c;
    cols[cb] = col;
    bias[cb] = bsel[col];
  }

  // ---- prologue: stage QH, prefetch tile 0 + trig 0 ----
  QH[tid] = qhat[(size_t)b * 512 + tid];
  s16x8 pf0, pf1, pf2, pf3;
  float2 ptr0, ptr1;
  {
    const s16x8* src = (const s16x8*)&xp[(size_t)blkrow0 * 256];
    pf0 = src[tid]; pf1 = src[tid + 512]; pf2 = src[tid + 1024]; pf3 = src[tid + 1536];
    int e0 = tid, e1 = tid + 512;
    ptr0 = trig[(size_t)((blkrow0 & 4095) + (e0 >> 4)) * 16 + (e0 & 15)];
    ptr1 = trig[(size_t)((blkrow0 & 4095) + (e1 >> 4)) * 16 + (e1 & 15)];
  }

  for (int t = 0; t < 4; ++t) {
    const int row0 = blkrow0 + t * 64;
    const int n0 = row0 & 4095;

    BAR_LGKM();   // prior-tile epilogue LDS reads complete
    // ---- write staged tile + trig (compiler waits vmcnt for pf/ptr) ----
    {
      s16x8* dst = (s16x8*)A;
      dst[tid] = pf0; dst[tid + 512] = pf1; dst[tid + 1024] = pf2; dst[tid + 1536] = pf3;
      TR[tid] = ptr0; TR[tid + 512] = ptr1;
    }
    BAR_LGKM();   // tile + trig visible

    // ---- issue next-tile prefetch (in flight across this tile's compute) ----
    if (t < 3) {
      const s16x8* src = (const s16x8*)&xp[(size_t)(row0 + 64) * 256];
      pf0 = src[tid]; pf1 = src[tid + 512]; pf2 = src[tid + 1024]; pf3 = src[tid + 1536];
      int e0 = tid, e1 = tid + 512;
      ptr0 = trig[(size_t)((n0 + 64) + (e0 >> 4)) * 16 + (e0 & 15)];
      ptr1 = trig[(size_t)((n0 + 64) + (e1 >> 4)) * 16 + (e1 & 15)];
    }

    // ---- GEMM (role-selected weights), two col-halves ----
    f32x4 acc[4][4];
#pragma unroll
    for (int rb = 0; rb < 4; ++rb)
#pragma unroll
      for (int cb = 0; cb < 4; ++cb) acc[rb][cb] = (f32x4){0.f, 0.f, 0.f, 0.f};
#pragma unroll
    for (int h = 0; h < 2; ++h) {
      s16x8 bfr[8][2];
#pragma unroll
      for (int ks = 0; ks < 8; ++ks)
#pragma unroll
        for (int j = 0; j < 2; ++j)
          bfr[ks][j] = *(const s16x8*)&wsel[(size_t)(w * 64 + (h * 2 + j) * 16 + c) * 256 + ks * 32 + g * 8];
#pragma unroll
      for (int ks = 0; ks < 8; ++ks) {
        s16x8 af[4];
#pragma unroll
        for (int rb = 0; rb < 4; ++rb) {
          int row = rb * 16 + c; int kc = ks * 4 + g;
          af[rb] = *(const s16x8*)&A[row * 256 + ((kc ^ (row & 7)) * 8)];
        }
#pragma unroll
        for (int rb = 0; rb < 4; ++rb)
#pragma unroll
          for (int j = 0; j < 2; ++j)
            acc[rb][h * 2 + j] = __builtin_amdgcn_mfma_f32_16x16x32_bf16(af[rb], bfr[ks][j], acc[rb][h * 2 + j], 0, 0, 0);
      }
    }
    BAR_LGKM();   // all A reads done (V waves may overwrite A)

    if (kv == 0) {
      // ---- K epilogue: bias + RoPE -> K2 (swizzled bf16) ----
#pragma unroll
      for (int rb = 0; rb < 4; ++rb)
#pragma unroll
        for (int cb = 0; cb < 4; ++cb) {
          int pp = (cols[cb] >> 1) & 15;
#pragma unroll
          for (int r = 0; r < 4; ++r) {
            int row = rb * 16 + g * 4 + r;
            float v = acc[rb][cb][r] + bias[cb];
            float pv = __shfl_xor(v, 1, 64);
            float2 cs2 = TR[row * 16 + pp];
            float rv = (c & 1) ? fmaf(v, cs2.x, pv * cs2.y)
                               : fmaf(v, cs2.x, -pv * cs2.y);
            K2[row * 256 + (cols[cb] ^ ((row & 7) * 8))] = f2bf(rv);
          }
        }
    } else {
      // ---- V epilogue: bias -> A (plain layout) ----
#pragma unroll
      for (int rb = 0; rb < 4; ++rb)
#pragma unroll
        for (int r = 0; r < 4; ++r) {
          int row = rb * 16 + g * 4 + r;
#pragma unroll
          for (int cb = 0; cb < 4; ++cb)
            A[row * 256 + cols[cb]] = f2bf(acc[rb][cb][r] + bias[cb]);
        }
    }
    BAR_LGKM();   // K2 + V visible

    // ---- epilogue: coalesced vws write + data-parallel scores ----
    {
      int row = tid >> 3, hh = tid & 7;
      const s16x8* src = (const s16x8*)&A[row * 256 + hh * 32];
      s16x8 v0 = src[0], v1 = src[1], v2 = src[2], v3 = src[3];
      s16x8* dst = (s16x8*)&vws[((size_t)(b * 8 + hh) * 4096 + n0 + row) * 32];
      dst[0] = v0; dst[1] = v1; dst[2] = v2; dst[3] = v3;
    }
    {
      int h = w8, row = l;
      float ssq = 0.f, d0 = 0.f, d1 = 0.f;
#pragma unroll
      for (int j = 0; j < 4; ++j) {
        s16x8 kvv = *(const s16x8*)&K2[row * 256 + (((h * 4 + j) ^ (row & 7)) * 8)];
#pragma unroll
        for (int t8 = 0; t8 < 8; ++t8) {
          float kf = bf2f((unsigned short)kvv[t8]);
          int col = h * 32 + j * 8 + t8;
          ssq = fmaf(kf, kf, ssq);
          d0 = fmaf(kf, QH[col], d0);
          d1 = fmaf(kf, QH[256 + col], d1);
        }
      }
      float is = 0.17677669529663687f / fmaxf(sqrtf(ssq), 1e-12f);
      scores[(size_t)((b * 8 + h) * 2 + 0) * 4096 + n0 + row] = d0 * is;
      scores[(size_t)((b * 8 + h) * 2 + 1) * 4096 + n0 + row] = d1 * is;
    }
  }
}

// ---------------- attention (unchanged, verified) ----------------
__global__ __launch_bounds__(256) void attn_kernel(
    const float* __restrict__ scores,
    const unsigned short* __restrict__ vws,
    float* __restrict__ out_attn) {
  int b = blockIdx.x >> 3, h = blockIdx.x & 7;
  const float* s0p = scores + (size_t)((b * 8 + h) * 2 + 0) * 4096;
  const float* s1p = scores + (size_t)((b * 8 + h) * 2 + 1) * 4096;
  float sa[16], sb[16];
  float a1 = 0.f, a2 = 0.f, b1 = 0.f, b2 = 0.f;
#pragma unroll
  for (int i = 0; i < 16; ++i) {
    int k = i * 256 + TID;
    sa[i] = s0p[k]; sb[i] = s1p[k];
    a1 += sa[i]; a2 += sa[i] * sa[i];
    b1 += sb[i]; b2 += sb[i] * sb[i];
  }
  __shared__ float red[16];
  int w = TID >> 6;
#pragma unroll
  for (int m = 1; m < 64; m <<= 1) {
    a1 += __shfl_xor(a1, m, 64); a2 += __shfl_xor(a2, m, 64);
    b1 += __shfl_xor(b1, m, 64); b2 += __shfl_xor(b2, m, 64);
  }
  if ((TID & 63) == 0) { red[w * 4] = a1; red[w * 4 + 1] = a2; red[w * 4 + 2] = b1; red[w * 4 + 3] = b2; }
  __syncthreads();
  a1 = red[0] + red[4] + red[8] + red[12];
  a2 = red[1] + red[5] + red[9] + red[13];
  b1 = red[2] + red[6] + red[10] + red[14];
  b2 = red[3] + red[7] + red[11] + red[15];
  float va = (a2 - a1 * a1 * (1.f / 4096.f)) * (1.f / 4095.f);
  float vb = (b2 - b1 * b1 * (1.f / 4096.f)) * (1.f / 4095.f);
  float sga = fmaxf(sqrtf(fmaxf(va, 0.f)), 1e-3f);
  float sgb = fmaxf(sqrtf(fmaxf(vb, 0.f)), 1e-3f);
  float ia = 0.5f / sga, ib = 0.5f / sgb;
  float fa = 5.f * sga, fb = 5.f * sgb;
  float ea = 0.f, eb = 0.f;
#pragma unroll
  for (int i = 0; i < 16; ++i) {
    sa[i] = __expf(tanhf(sa[i] * ia) * fa);
    sb[i] = __expf(tanhf(sb[i] * ib) * fb);
    ea += sa[i]; eb += sb[i];
  }
#pragma unroll
  for (int m = 1; m < 64; m <<= 1) { ea += __shfl_xor(ea, m, 64); eb += __shfl_xor(eb, m, 64); }
  __syncthreads();
  if ((TID & 63) == 0) { red[w * 2] = ea; red[w * 2 + 1] = eb; }
  __syncthreads();
  ea = red[0] + red[2] + red[4] + red[6];
  eb = red[1] + red[3] + red[5] + red[7];
  float iea = 1.f / ea, ieb = 1.f / eb;
  float oa[32], ob[32];
#pragma unroll
  for (int d = 0; d < 32; ++d) { oa[d] = 0.f; ob[d] = 0.f; }
  const unsigned short* vbase = vws + (size_t)(b * 8 + h) * 4096 * 32;
#pragma unroll 4
  for (int i = 0; i < 16; ++i) {
    int k = i * 256 + TID;
    float wa = fmaf(sa[i], iea, 1e-4f);
    float wb = fmaf(sb[i], ieb, 1e-4f);
    const s16x8* vp = (const s16x8*)(vbase + (size_t)k * 32);
#pragma unroll
    for (int j = 0; j < 4; ++j) {
      s16x8 vv = vp[j];
#pragma unroll
      for (int t = 0; t < 8; ++t) {
        float vf = bf2f((unsigned short)vv[t]);
        oa[j * 8 + t] = fmaf(wa, vf, oa[j * 8 + t]);
        ob[j * 8 + t] = fmaf(wb, vf, ob[j * 8 + t]);
      }
    }
  }
#pragma unroll
  for (int m = 1; m < 64; m <<= 1) {
#pragma unroll
    for (int d = 0; d < 32; ++d) { oa[d] += __shfl_xor(oa[d], m, 64); ob[d] += __shfl_xor(ob[d], m, 64); }
  }
  __shared__ float R[4][64];
  if ((TID & 63) == 0) {
#pragma unroll
    for (int d = 0; d < 32; ++d) { R[w][d] = oa[d]; R[w][32 + d] = ob[d]; }
  }
  __syncthreads();
  if (TID < 64) {
    float s = R[0][TID] + R[1][TID] + R[2][TID] + R[3][TID];
    int q = TID >> 5, d = TID & 31;
    out_attn[(b * 2 + q) * 256 + h * 32 + d] = s;
  }
}

// ---------------- final: pooled + logits ----------------
__global__ __launch_bounds__(256) void final_kernel(
    const float* __restrict__ attn, const float* __restrict__ fc_w,
    const float* __restrict__ fc_b, float* __restrict__ out_pooled,
    float* __restrict__ out_logits) {
  int b = blockIdx.x;
  __shared__ float P[256];
  float p = 0.5f * (attn[(b * 2) * 256 + TID] + attn[(b * 2 + 1) * 256 + TID]);
  out_pooled[b * 256 + TID] = p;
  P[TID] = p;
  __syncthreads();
  if (TID < 40) {
    float acc = fc_b[TID];
#pragma unroll 8
    for (int i = 0; i < 256; ++i) acc = fmaf(P[i], fc_w[i * 40 + TID], acc);
    out_logits[b * 40 + TID] = acc;
  }
}

extern "C" void kernel_launch(void* const* d_in, const int* in_sizes, int n_in,
                              void* d_out, int out_size, void* d_ws, size_t ws_size,
                              hipStream_t stream) {
  (void)in_sizes; (void)n_in; (void)out_size; (void)ws_size;
  const float* eeg_feat  = (const float*)d_in[0];
  const float* stim_feat = (const float*)d_in[1];
  const float* temp_feat = (const float*)d_in[2];
  const float* eeg_w = (const float*)d_in[3];
  const float* eeg_b = (const float*)d_in[4];
  const float* stim_w = (const float*)d_in[5];
  const float* stim_b = (const float*)d_in[6];
  const float* temp_w = (const float*)d_in[7];
  const float* temp_b = (const float*)d_in[8];
  const float* q_w = (const float*)d_in[9];
  const float* q_b = (const float*)d_in[10];
  const float* k_w = (const float*)d_in[11];
  const float* k_b = (const float*)d_in[12];
  const float* v_w = (const float*)d_in[13];
  const float* v_b = (const float*)d_in[14];
  const float* fc_w = (const float*)d_in[15];
  const float* fc_b = (const float*)d_in[16];
  const float* lnq_g = (const float*)d_in[17];
  const float* lnq_b = (const float*)d_in[18];
  const float* lnk_g = (const float*)d_in[19];
  const float* lnk_b = (const float*)d_in[20];

  char* ws = (char*)d_ws;
  unsigned short* wt  = (unsigned short*)(ws + 0);         // 384 KB
  float2* trig        = (float2*)(ws + 393216);            // 512 KB
  float* qhat         = (float*)(ws + 917504);             // 64 KB
  float* scores       = (float*)(ws + 1048576);            // 8 MB
  unsigned short* xp  = (unsigned short*)(ws + 9437184);   // 64 MB (LN'd X, swizzled bf16)
  unsigned short* vws = (unsigned short*)(ws + 76546048);  // 64 MB

  float* out = (float*)d_out;
  float* out_logits = out;                 // 32*40
  float* out_pooled = out + 1280;          // 32*256
  float* out_attn   = out + 9472;          // 32*2*256
  float* out_query  = out + 25856;         // 32*2*256

  prep_kernel<<<1024, 256, 0, stream>>>(eeg_w, k_w, v_w, wt, trig);
  q_kernel<<<64, 256, 0, stream>>>(stim_feat, temp_feat, stim_w, stim_b,
                                   temp_w, temp_b, q_w, q_b, lnq_g, lnq_b,
                                   out_query, qhat);
  eeg_ln_kernel<<<2048, 256, 0, stream>>>(eeg_feat, eeg_b, lnk_g, lnk_b, wt, xp);
  kv_kernel<<<512, 512, 0, stream>>>(xp, k_b, v_b, wt + 65536, wt + 131072,
                                     trig, qhat, scores, vws);
  attn_kernel<<<256, 256, 0, stream>>>(scores, vws, out_attn);
  final_kernel<<<32, 256, 0, stream>>>(out_attn, fc_w, fc_b, out_pooled, out_logits);
}

// Round 4
// 283.267 us; speedup vs baseline: 1.5470x; 1.5470x over previous
//
#include <hip/hip_runtime.h>
#include <hip/hip_bf16.h>
#include <math.h>

#define TID ((int)threadIdx.x)

typedef float f32x4 __attribute__((ext_vector_type(4)));
typedef short s16x8 __attribute__((ext_vector_type(8)));

__device__ __forceinline__ unsigned short f2bf(float f) {
  union { float f; unsigned u; } v; v.f = f;
  unsigned r = v.u + 0x7FFFu + ((v.u >> 16) & 1u);
  return (unsigned short)(r >> 16);
}
__device__ __forceinline__ float bf2f(unsigned short h) {
  union { unsigned u; float f; } v; v.u = ((unsigned)h) << 16;
  return v.f;
}

// ---------------- prep: eeg_w/k_w transpose->bf16 + RoPE trig table ----------------
// wt: m in {eeg,k}: wt[m*65536 + col*256 + k]; trig[n*16+p] = (cos,sin)(n*10000^(-p/16))
__global__ void prep_kernel(const float* __restrict__ eeg_w,
                            const float* __restrict__ k_w,
                            unsigned short* __restrict__ wt,
                            float2* __restrict__ trig) {
  int gid = blockIdx.x * 256 + TID;            // grid = 768*256 = 196608 exactly
  if (gid < 2 * 65536) {
    int m = gid >> 16, e = gid & 65535;
    int i = e >> 8, j = e & 255;
    const float* W = (m == 0) ? eeg_w : k_w;
    wt[m * 65536 + j * 256 + i] = f2bf(W[i * 256 + j]);
  } else {
    int e = gid - 2 * 65536;                   // < 65536
    int n = e >> 4, p = e & 15;
    float inv = exp2f(-(float)p * 0.8304820237218406f);  // 10000^(-p/16)
    float a = (float)n * inv;
    trig[e] = make_float2(cosf(a), sinf(a));
  }
}

// ---------------- query path (unchanged, verified) ----------------
__global__ __launch_bounds__(256) void q_kernel(
    const float* __restrict__ stim_feat, const float* __restrict__ temp_feat,
    const float* __restrict__ stim_w, const float* __restrict__ stim_b,
    const float* __restrict__ temp_w, const float* __restrict__ temp_b,
    const float* __restrict__ q_w, const float* __restrict__ q_b,
    const float* __restrict__ lnq_g, const float* __restrict__ lnq_b,
    float* __restrict__ out_query, float* __restrict__ qhat) {
  int b = blockIdx.x >> 1, q = blockIdx.x & 1;
  __shared__ float f[256];
  __shared__ float red[8];
  const float* feat = (q ? temp_feat : stim_feat) + b * 256;
  const float* W = q ? temp_w : stim_w;
  const float* bias = q ? temp_b : stim_b;
  f[TID] = feat[TID];
  __syncthreads();
  float acc = bias[TID];
#pragma unroll 8
  for (int i = 0; i < 256; ++i) acc = fmaf(f[i], W[i * 256 + TID], acc);
  float s1 = acc, s2 = acc * acc;
#pragma unroll
  for (int m = 1; m < 64; m <<= 1) { s1 += __shfl_xor(s1, m, 64); s2 += __shfl_xor(s2, m, 64); }
  if ((TID & 63) == 0) { red[TID >> 6] = s1; red[4 + (TID >> 6)] = s2; }
  __syncthreads();
  s1 = red[0] + red[1] + red[2] + red[3];
  s2 = red[4] + red[5] + red[6] + red[7];
  float mean = s1 * (1.f / 256.f);
  float var = s2 * (1.f / 256.f) - mean * mean;
  float rstd = rsqrtf(var + 1e-5f);
  float qln = (acc - mean) * rstd * lnq_g[TID] + lnq_b[TID];
  out_query[(b * 2 + q) * 256 + TID] = qln;
  __syncthreads();
  f[TID] = qln;
  __syncthreads();
  float a2 = q_b[TID];
#pragma unroll 8
  for (int i = 0; i < 256; ++i) a2 = fmaf(f[i], q_w[i * 256 + TID], a2);
  __syncthreads();
  f[TID] = a2;
  __syncthreads();
  float partner = f[TID ^ 1];
  int p = (TID >> 1) & 15;
  float inv = exp2f(-(float)p * 0.8304820237218406f);
  float ang = (float)q * inv;
  float cc_ = cosf(ang), ss_ = sinf(ang);
  float r = (TID & 1) ? fmaf(a2, cc_, partner * ss_) : fmaf(a2, cc_, -partner * ss_);
  float sq = r * r;
#pragma unroll
  for (int m = 1; m < 32; m <<= 1) sq += __shfl_xor(sq, m, 32);
  float rs = 1.f / fmaxf(sqrtf(sq), 1e-12f);
  qhat[(b * 2 + q) * 256 + TID] = r * rs;
}

// ---------------- main: eeg proj -> LN -> X' dump + K proj -> scores ----------------
__global__ __launch_bounds__(256, 3) void main_kernel(
    const float* __restrict__ x,
    const float* __restrict__ eeg_b,
    const float* __restrict__ k_b,
    const float* __restrict__ lnk_g,
    const float* __restrict__ lnk_b,
    const unsigned short* __restrict__ wt_eeg,
    const unsigned short* __restrict__ wt_k,
    const float2* __restrict__ trig,
    const float* __restrict__ qhat,
    float* __restrict__ scores,
    unsigned short* __restrict__ xp) {

  __shared__ __align__(16) unsigned short A[64 * 256];  // 32KB: X'/LN tile, then K-hat (swizzled)
  __shared__ float PS[64 * 9];                          // LN partials (pad 9); later aliased as QH
  __shared__ float2 ST[64];                             // (mean, rstd) per row

  float* QH = PS;   // qhat staged here after LN stats consumed (time-disjoint)

  const int tid = TID;
  const int w = tid >> 6, l = tid & 63, g = l >> 4, c = l & 15;
  const int r0 = blockIdx.x * 64;
  const int b = r0 >> 12;
  const int n0 = r0 & 4095;

  // ---- stage X (fp32 -> bf16, swizzled) ----
#pragma unroll
  for (int i = 0; i < 8; ++i) {
    int ch = i * 256 + tid;
    int row = ch >> 5, cc = ch & 31;
    const float4* gp = (const float4*)(x + (size_t)(r0 + row) * 256 + cc * 8);
    float4 u0 = gp[0], u1 = gp[1];
    s16x8 pk;
    pk[0] = (short)f2bf(u0.x); pk[1] = (short)f2bf(u0.y);
    pk[2] = (short)f2bf(u0.z); pk[3] = (short)f2bf(u0.w);
    pk[4] = (short)f2bf(u1.x); pk[5] = (short)f2bf(u1.y);
    pk[6] = (short)f2bf(u1.z); pk[7] = (short)f2bf(u1.w);
    *(s16x8*)&A[row * 256 + ((cc ^ (row & 7)) * 8)] = pk;
  }
  __syncthreads();

  f32x4 acc[4][4];

#define DO_GEMM(WT) do {                                                          \
    _Pragma("unroll") for (int rb = 0; rb < 4; ++rb)                              \
      _Pragma("unroll") for (int cb = 0; cb < 4; ++cb)                            \
        acc[rb][cb] = (f32x4){0.f, 0.f, 0.f, 0.f};                                \
    _Pragma("unroll") for (int ks = 0; ks < 8; ++ks) {                            \
      s16x8 af[4]; s16x8 bfr[4];                                                  \
      _Pragma("unroll") for (int rb = 0; rb < 4; ++rb) {                          \
        int row = rb * 16 + c; int kc = ks * 4 + g;                               \
        af[rb] = *(const s16x8*)&A[row * 256 + ((kc ^ (row & 7)) * 8)];           \
      }                                                                           \
      _Pragma("unroll") for (int cb = 0; cb < 4; ++cb) {                          \
        int col = w * 64 + cb * 16 + c;                                           \
        bfr[cb] = *(const s16x8*)&(WT)[col * 256 + ks * 32 + g * 8];              \
      }                                                                           \
      _Pragma("unroll") for (int rb = 0; rb < 4; ++rb)                            \
        _Pragma("unroll") for (int cb = 0; cb < 4; ++cb)                          \
          acc[rb][cb] = __builtin_amdgcn_mfma_f32_16x16x32_bf16(                  \
              af[rb], bfr[cb], acc[rb][cb], 0, 0, 0);                             \
    } } while (0)

  float ebias[4], kbias[4], gg[4], bb[4];
  int cols[4];
#pragma unroll
  for (int cb = 0; cb < 4; ++cb) {
    int col = w * 64 + cb * 16 + c;
    cols[cb] = col;
    ebias[cb] = eeg_b[col]; kbias[cb] = k_b[col];
    gg[cb] = lnk_g[col]; bb[cb] = lnk_b[col];
  }

  // ---- GEMM1: eeg projection ----
  DO_GEMM(wt_eeg);

  // ---- LN stats ----
  {
    float ps[4][4], pq[4][4];
#pragma unroll
    for (int rb = 0; rb < 4; ++rb)
#pragma unroll
      for (int r = 0; r < 4; ++r) {
        float s = 0.f, q2 = 0.f;
#pragma unroll
        for (int cb = 0; cb < 4; ++cb) {
          float v = acc[rb][cb][r] + ebias[cb];
          s += v; q2 += v * v;
        }
        ps[rb][r] = s; pq[rb][r] = q2;
      }
#pragma unroll
    for (int m = 1; m < 16; m <<= 1)
#pragma unroll
      for (int rb = 0; rb < 4; ++rb)
#pragma unroll
        for (int r = 0; r < 4; ++r) {
          ps[rb][r] += __shfl_xor(ps[rb][r], m, 64);
          pq[rb][r] += __shfl_xor(pq[rb][r], m, 64);
        }
    float outS = 0.f, outQ = 0.f;
#pragma unroll
    for (int rb = 0; rb < 4; ++rb)
#pragma unroll
      for (int r = 0; r < 4; ++r)
        if (c == rb * 4 + r) { outS = ps[rb][r]; outQ = pq[rb][r]; }
    int row = (c >> 2) * 16 + g * 4 + (c & 3);
    PS[row * 9 + w * 2 + 0] = outS;
    PS[row * 9 + w * 2 + 1] = outQ;
  }
  __syncthreads();
  if (tid < 64) {
    float s = PS[tid * 9 + 0] + PS[tid * 9 + 2] + PS[tid * 9 + 4] + PS[tid * 9 + 6];
    float q2 = PS[tid * 9 + 1] + PS[tid * 9 + 3] + PS[tid * 9 + 5] + PS[tid * 9 + 7];
    float mean = s * (1.f / 256.f);
    float var = q2 * (1.f / 256.f) - mean * mean;
    ST[tid] = make_float2(mean, rsqrtf(var + 1e-5f));
  }
  __syncthreads();

  // ---- LN apply -> A (swizzled); stage qhat into QH (PS dead now) ----
  QH[tid] = qhat[(size_t)b * 512 + tid];
  QH[256 + tid] = qhat[(size_t)b * 512 + 256 + tid];
#pragma unroll
  for (int rb = 0; rb < 4; ++rb)
#pragma unroll
    for (int r = 0; r < 4; ++r) {
      int row = rb * 16 + g * 4 + r;
      float2 st = ST[row];
#pragma unroll
      for (int cb = 0; cb < 4; ++cb) {
        float v = (acc[rb][cb][r] + ebias[cb] - st.x) * st.y * gg[cb] + bb[cb];
        A[row * 256 + (cols[cb] ^ ((row & 7) * 8))] = f2bf(v);
      }
    }
  __syncthreads();

  // ---- X' dump to xp (natural layout, coalesced) ----
#pragma unroll
  for (int i = 0; i < 8; ++i) {
    int e = i * 256 + tid;
    int row = e >> 5, u = e & 31;
    s16x8 v = *(const s16x8*)&A[row * 256 + ((u ^ (row & 7)) * 8)];
    *(s16x8*)&xp[(size_t)(r0 + row) * 256 + u * 8] = v;
  }

  // ---- GEMM2: K projection ----
  DO_GEMM(wt_k);
  __syncthreads();   // all A reads (GEMM2 + dump) done

  // ---- K epilogue: bias -> bf16 -> A (swizzled). RoPE deferred to score phase. ----
#pragma unroll
  for (int rb = 0; rb < 4; ++rb)
#pragma unroll
    for (int r = 0; r < 4; ++r) {
      int row = rb * 16 + g * 4 + r;
#pragma unroll
      for (int cb = 0; cb < 4; ++cb)
        A[row * 256 + (cols[cb] ^ ((row & 7) * 8))] = f2bf(acc[rb][cb][r] + kbias[cb]);
    }
  __syncthreads();

  // ---- score phase: per (row, head): RoPE pairs + ssq + dot(Q0,Q1), no cross-lane ----
#pragma unroll
  for (int cell = 0; cell < 2; ++cell) {
    int h = cell * 4 + w;
    int row = l;
    const float2* tgp = trig + (size_t)(n0 + row) * 16;
    float2 tg[16];
#pragma unroll
    for (int i = 0; i < 16; ++i) tg[i] = tgp[i];   // contiguous 128B/lane, rows contiguous
    float ssq = 0.f, d0 = 0.f, d1 = 0.f;
#pragma unroll
    for (int j = 0; j < 4; ++j) {
      s16x8 kvv = *(const s16x8*)&A[row * 256 + (((h * 4 + j) ^ (row & 7)) * 8)];
#pragma unroll
      for (int t = 0; t < 4; ++t) {
        float e0 = bf2f((unsigned short)kvv[2 * t]);
        float e1 = bf2f((unsigned short)kvv[2 * t + 1]);
        float2 cs = tg[j * 4 + t];
        float rv0 = e0 * cs.x - e1 * cs.y;
        float rv1 = fmaf(e1, cs.x, e0 * cs.y);
        int col = h * 32 + j * 8 + 2 * t;
        ssq = fmaf(rv0, rv0, fmaf(rv1, rv1, ssq));
        d0 = fmaf(rv0, QH[col], fmaf(rv1, QH[col + 1], d0));
        d1 = fmaf(rv0, QH[256 + col], fmaf(rv1, QH[256 + col + 1], d1));
      }
    }
    float is = 0.17677669529663687f / fmaxf(sqrtf(ssq), 1e-12f);
    scores[(size_t)((b * 8 + h) * 2 + 0) * 4096 + n0 + row] = d0 * is;
    scores[(size_t)((b * 8 + h) * 2 + 1) * 4096 + n0 + row] = d1 * is;
  }
#undef DO_GEMM
}

// ---------------- s1: score stats -> tanh rescale -> softmax -> weights w ----------------
__global__ __launch_bounds__(256) void wgt_kernel(
    const float* __restrict__ scores, float* __restrict__ wbuf) {
  int b = blockIdx.x >> 3, h = blockIdx.x & 7;
  const float* s0p = scores + (size_t)((b * 8 + h) * 2 + 0) * 4096;
  const float* s1p = scores + (size_t)((b * 8 + h) * 2 + 1) * 4096;
  float sa[16], sb[16];
  float a1 = 0.f, a2 = 0.f, b1 = 0.f, b2 = 0.f;
#pragma unroll
  for (int i = 0; i < 16; ++i) {
    int k = i * 256 + TID;
    sa[i] = s0p[k]; sb[i] = s1p[k];
    a1 += sa[i]; a2 += sa[i] * sa[i];
    b1 += sb[i]; b2 += sb[i] * sb[i];
  }
  __shared__ float red[16];
  int w = TID >> 6;
#pragma unroll
  for (int m = 1; m < 64; m <<= 1) {
    a1 += __shfl_xor(a1, m, 64); a2 += __shfl_xor(a2, m, 64);
    b1 += __shfl_xor(b1, m, 64); b2 += __shfl_xor(b2, m, 64);
  }
  if ((TID & 63) == 0) { red[w * 4] = a1; red[w * 4 + 1] = a2; red[w * 4 + 2] = b1; red[w * 4 + 3] = b2; }
  __syncthreads();
  a1 = red[0] + red[4] + red[8] + red[12];
  a2 = red[1] + red[5] + red[9] + red[13];
  b1 = red[2] + red[6] + red[10] + red[14];
  b2 = red[3] + red[7] + red[11] + red[15];
  float va = (a2 - a1 * a1 * (1.f / 4096.f)) * (1.f / 4095.f);   // ddof=1
  float vb = (b2 - b1 * b1 * (1.f / 4096.f)) * (1.f / 4095.f);
  float sga = fmaxf(sqrtf(fmaxf(va, 0.f)), 1e-3f);
  float sgb = fmaxf(sqrtf(fmaxf(vb, 0.f)), 1e-3f);
  float ia = 0.5f / sga, ib = 0.5f / sgb;
  float fa = 5.f * sga, fb = 5.f * sgb;
  float ea = 0.f, eb = 0.f;
#pragma unroll
  for (int i = 0; i < 16; ++i) {
    sa[i] = __expf(tanhf(sa[i] * ia) * fa);    // |arg| <= 5*sigma: no max-sub needed
    sb[i] = __expf(tanhf(sb[i] * ib) * fb);
    ea += sa[i]; eb += sb[i];
  }
#pragma unroll
  for (int m = 1; m < 64; m <<= 1) { ea += __shfl_xor(ea, m, 64); eb += __shfl_xor(eb, m, 64); }
  __syncthreads();
  if ((TID & 63) == 0) { red[w * 2] = ea; red[w * 2 + 1] = eb; }
  __syncthreads();
  ea = red[0] + red[2] + red[4] + red[6];
  eb = red[1] + red[3] + red[5] + red[7];
  float iea = 1.f / ea, ieb = 1.f / eb;   // denom (1+1e-8) == 1.0f in fp32
  float* w0 = wbuf + ((size_t)(b * 16) + h * 2 + 0) * 4096;
  float* w1 = w0 + 4096;
#pragma unroll
  for (int i = 0; i < 16; ++i) {
    int k = i * 256 + TID;
    w0[k] = fmaf(sa[i], iea, 1e-4f);
    w1[k] = fmaf(sb[i], ieb, 1e-4f);
  }
}

// ---------------- s2: y[b,hq,:] partial = sum_n w[b,hq,n] * X'[n,:] over 128-row slabs ----------------
__global__ __launch_bounds__(256) void ysum_kernel(
    const unsigned short* __restrict__ xp, const float* __restrict__ wbuf,
    float* __restrict__ ypart) {
  int b = blockIdx.x >> 5, slab = blockIdx.x & 31;
  int h = TID >> 5, cg = TID & 31;                 // 8 heads x 32 col-groups
  const unsigned short* xb = xp + ((size_t)b * 4096 + slab * 128) * 256 + cg * 8;
  const float* w0 = wbuf + ((size_t)(b * 16) + h * 2 + 0) * 4096 + slab * 128;
  const float* w1 = w0 + 4096;
  float y0[8], y1[8];
#pragma unroll
  for (int t = 0; t < 8; ++t) { y0[t] = 0.f; y1[t] = 0.f; }
#pragma unroll 4
  for (int r = 0; r < 128; ++r) {
    s16x8 xv = *(const s16x8*)(xb + (size_t)r * 256);
    float wa = w0[r], wc = w1[r];
#pragma unroll
    for (int t = 0; t < 8; ++t) {
      float xf = bf2f((unsigned short)xv[t]);
      y0[t] = fmaf(wa, xf, y0[t]);
      y1[t] = fmaf(wc, xf, y1[t]);
    }
  }
  float* yp = ypart + (((size_t)(b * 32 + slab) * 16) + h * 2) * 256 + cg * 8;
  *(float4*)&yp[0] = (float4){y0[0], y0[1], y0[2], y0[3]};
  *(float4*)&yp[4] = (float4){y0[4], y0[5], y0[6], y0[7]};
  *(float4*)&yp[256] = (float4){y1[0], y1[1], y1[2], y1[3]};
  *(float4*)&yp[260] = (float4){y1[4], y1[5], y1[6], y1[7]};
}

// ---------------- s3: reduce y, @ v_w + 1.4096*v_b -> attn_out, pooled, logits ----------------
__global__ __launch_bounds__(256) void finish_kernel(
    const float* __restrict__ ypart, const float* __restrict__ v_w,
    const float* __restrict__ v_b, const float* __restrict__ fc_w,
    const float* __restrict__ fc_b, float* __restrict__ out_attn,
    float* __restrict__ out_pooled, float* __restrict__ out_logits) {
  int b = blockIdx.x;
  __shared__ float Y[16][256];
  __shared__ float ATT[2][256];
  __shared__ float P[256];
  for (int idx = TID; idx < 4096; idx += 256) {
    int hq = idx >> 8, cc = idx & 255;
    float s = 0.f;
#pragma unroll 8
    for (int sl = 0; sl < 32; ++sl)
      s += ypart[(((size_t)(b * 32 + sl) * 16) + hq) * 256 + cc];
    Y[hq][cc] = s;
  }
  __syncthreads();
#pragma unroll
  for (int o = TID; o < 512; o += 256) {
    int q = o >> 8, dout = o & 255;
    int hq = (dout >> 5) * 2 + q;
    float acc = 1.4096f * v_b[dout];     // sum(w) = 1 + 4096e-4 exactly
#pragma unroll 8
    for (int c2 = 0; c2 < 256; ++c2)
      acc = fmaf(Y[hq][c2], v_w[c2 * 256 + dout], acc);
    out_attn[(b * 2 + q) * 256 + dout] = acc;
    ATT[q][dout] = acc;
  }
  __syncthreads();
  float p = 0.5f * (ATT[0][TID] + ATT[1][TID]);
  out_pooled[b * 256 + TID] = p;
  P[TID] = p;
  __syncthreads();
  if (TID < 40) {
    float acc = fc_b[TID];
#pragma unroll 8
    for (int i = 0; i < 256; ++i) acc = fmaf(P[i], fc_w[i * 40 + TID], acc);
    out_logits[b * 40 + TID] = acc;
  }
}

extern "C" void kernel_launch(void* const* d_in, const int* in_sizes, int n_in,
                              void* d_out, int out_size, void* d_ws, size_t ws_size,
                              hipStream_t stream) {
  (void)in_sizes; (void)n_in; (void)out_size; (void)ws_size;
  const float* eeg_feat  = (const float*)d_in[0];
  const float* stim_feat = (const float*)d_in[1];
  const float* temp_feat = (const float*)d_in[2];
  const float* eeg_w = (const float*)d_in[3];
  const float* eeg_b = (const float*)d_in[4];
  const float* stim_w = (const float*)d_in[5];
  const float* stim_b = (const float*)d_in[6];
  const float* temp_w = (const float*)d_in[7];
  const float* temp_b = (const float*)d_in[8];
  const float* q_w = (const float*)d_in[9];
  const float* q_b = (const float*)d_in[10];
  const float* k_w = (const float*)d_in[11];
  const float* k_b = (const float*)d_in[12];
  const float* v_w = (const float*)d_in[13];
  const float* v_b = (const float*)d_in[14];
  const float* fc_w = (const float*)d_in[15];
  const float* fc_b = (const float*)d_in[16];
  const float* lnq_g = (const float*)d_in[17];
  const float* lnq_b = (const float*)d_in[18];
  const float* lnk_g = (const float*)d_in[19];
  const float* lnk_b = (const float*)d_in[20];

  char* ws = (char*)d_ws;
  unsigned short* wt  = (unsigned short*)(ws + 0);          // 256 KB (eeg^T, k^T bf16)
  float2* trig        = (float2*)(ws + 393216);             // 512 KB
  float* qhat         = (float*)(ws + 917504);              // 64 KB
  float* scores       = (float*)(ws + 1048576);             // 8 MB
  float* wbuf         = (float*)(ws + 9437184);             // 8 MB  (attn weights fp32)
  unsigned short* xp  = (unsigned short*)(ws + 17825792);   // 64 MB (LN'd X bf16, natural layout)
  float* ypart        = (float*)(ws + 84934656);            // 16 MB (y partials)

  float* out = (float*)d_out;
  float* out_logits = out;                 // 32*40
  float* out_pooled = out + 1280;          // 32*256
  float* out_attn   = out + 9472;          // 32*2*256
  float* out_query  = out + 25856;         // 32*2*256

  prep_kernel<<<768, 256, 0, stream>>>(eeg_w, k_w, wt, trig);
  q_kernel<<<64, 256, 0, stream>>>(stim_feat, temp_feat, stim_w, stim_b,
                                   temp_w, temp_b, q_w, q_b, lnq_g, lnq_b,
                                   out_query, qhat);
  main_kernel<<<2048, 256, 0, stream>>>(eeg_feat, eeg_b, k_b, lnk_g, lnk_b,
                                        wt, wt + 65536, trig, qhat, scores, xp);
  wgt_kernel<<<256, 256, 0, stream>>>(scores, wbuf);
  ysum_kernel<<<1024, 256, 0, stream>>>(xp, wbuf, ypart);
  finish_kernel<<<32, 256, 0, stream>>>(ypart, v_w, v_b, fc_w, fc_b,
                                        out_attn, out_pooled, out_logits);
}

// Round 5
// 279.397 us; speedup vs baseline: 1.5685x; 1.0139x over previous
//
#include <hip/hip_runtime.h>
#include <hip/hip_bf16.h>
#include <math.h>

#define TID ((int)threadIdx.x)

typedef float f32x4 __attribute__((ext_vector_type(4)));
typedef short s16x8 __attribute__((ext_vector_type(8)));

__device__ __forceinline__ unsigned short f2bf(float f) {
  union { float f; unsigned u; } v; v.f = f;
  unsigned r = v.u + 0x7FFFu + ((v.u >> 16) & 1u);
  return (unsigned short)(r >> 16);
}
__device__ __forceinline__ float bf2f(unsigned short h) {
  union { unsigned u; float f; } v; v.u = ((unsigned)h) << 16;
  return v.f;
}

// ---------------- prep: eeg_w/k_w transpose->bf16 + RoPE trig table ----------------
__global__ void prep_kernel(const float* __restrict__ eeg_w,
                            const float* __restrict__ k_w,
                            unsigned short* __restrict__ wt,
                            float2* __restrict__ trig) {
  int gid = blockIdx.x * 256 + TID;            // grid = 768*256 = 196608 exactly
  if (gid < 2 * 65536) {
    int m = gid >> 16, e = gid & 65535;
    int i = e >> 8, j = e & 255;
    const float* W = (m == 0) ? eeg_w : k_w;
    wt[m * 65536 + j * 256 + i] = f2bf(W[i * 256 + j]);
  } else {
    int e = gid - 2 * 65536;                   // < 65536
    int n = e >> 4, p = e & 15;
    float inv = exp2f(-(float)p * 0.8304820237218406f);  // 10000^(-p/16)
    float a = (float)n * inv;
    trig[e] = make_float2(cosf(a), sinf(a));
  }
}

// ---------------- query path (unchanged, verified) ----------------
__global__ __launch_bounds__(256) void q_kernel(
    const float* __restrict__ stim_feat, const float* __restrict__ temp_feat,
    const float* __restrict__ stim_w, const float* __restrict__ stim_b,
    const float* __restrict__ temp_w, const float* __restrict__ temp_b,
    const float* __restrict__ q_w, const float* __restrict__ q_b,
    const float* __restrict__ lnq_g, const float* __restrict__ lnq_b,
    float* __restrict__ out_query, float* __restrict__ qhat) {
  int b = blockIdx.x >> 1, q = blockIdx.x & 1;
  __shared__ float f[256];
  __shared__ float red[8];
  const float* feat = (q ? temp_feat : stim_feat) + b * 256;
  const float* W = q ? temp_w : stim_w;
  const float* bias = q ? temp_b : stim_b;
  f[TID] = feat[TID];
  __syncthreads();
  float acc = bias[TID];
#pragma unroll 8
  for (int i = 0; i < 256; ++i) acc = fmaf(f[i], W[i * 256 + TID], acc);
  float s1 = acc, s2 = acc * acc;
#pragma unroll
  for (int m = 1; m < 64; m <<= 1) { s1 += __shfl_xor(s1, m, 64); s2 += __shfl_xor(s2, m, 64); }
  if ((TID & 63) == 0) { red[TID >> 6] = s1; red[4 + (TID >> 6)] = s2; }
  __syncthreads();
  s1 = red[0] + red[1] + red[2] + red[3];
  s2 = red[4] + red[5] + red[6] + red[7];
  float mean = s1 * (1.f / 256.f);
  float var = s2 * (1.f / 256.f) - mean * mean;
  float rstd = rsqrtf(var + 1e-5f);
  float qln = (acc - mean) * rstd * lnq_g[TID] + lnq_b[TID];
  out_query[(b * 2 + q) * 256 + TID] = qln;
  __syncthreads();
  f[TID] = qln;
  __syncthreads();
  float a2 = q_b[TID];
#pragma unroll 8
  for (int i = 0; i < 256; ++i) a2 = fmaf(f[i], q_w[i * 256 + TID], a2);
  __syncthreads();
  f[TID] = a2;
  __syncthreads();
  float partner = f[TID ^ 1];
  int p = (TID >> 1) & 15;
  float inv = exp2f(-(float)p * 0.8304820237218406f);
  float ang = (float)q * inv;
  float cc_ = cosf(ang), ss_ = sinf(ang);
  float r = (TID & 1) ? fmaf(a2, cc_, partner * ss_) : fmaf(a2, cc_, -partner * ss_);
  float sq = r * r;
#pragma unroll
  for (int m = 1; m < 32; m <<= 1) sq += __shfl_xor(sq, m, 32);
  float rs = 1.f / fmaxf(sqrtf(sq), 1e-12f);
  qhat[(b * 2 + q) * 256 + TID] = r * rs;
}

// ---------------- main: 32-row tile: eeg proj -> LN -> X' dump + K proj -> scores ----------------
__global__ __launch_bounds__(256) void main_kernel(
    const float* __restrict__ x,
    const float* __restrict__ eeg_b,
    const float* __restrict__ k_b,
    const float* __restrict__ lnk_g,
    const float* __restrict__ lnk_b,
    const unsigned short* __restrict__ wt_eeg,
    const unsigned short* __restrict__ wt_k,
    const float2* __restrict__ trig,
    const float* __restrict__ qhat,
    float* __restrict__ scores,
    unsigned short* __restrict__ xp) {

  __shared__ __align__(16) unsigned short A[32 * 256];  // 16KB: X'/LN tile, then K (swizzled)
  __shared__ float PSQH[512];                           // LN partials (stride 9), then qhat
  __shared__ float2 ST[32];                             // (mean, rstd) per row

  const int tid = TID;
  const int w = tid >> 6, l = tid & 63, g = l >> 4, c = l & 15;
  const int r0 = blockIdx.x * 32;
  const int b = r0 >> 12;
  const int n0 = r0 & 4095;

  // ---- stage X (fp32 -> bf16, swizzled) ----
#pragma unroll
  for (int i = 0; i < 4; ++i) {
    int ch = i * 256 + tid;
    int row = ch >> 5, cc = ch & 31;
    const float4* gp = (const float4*)(x + (size_t)(r0 + row) * 256 + cc * 8);
    float4 u0 = gp[0], u1 = gp[1];
    s16x8 pk;
    pk[0] = (short)f2bf(u0.x); pk[1] = (short)f2bf(u0.y);
    pk[2] = (short)f2bf(u0.z); pk[3] = (short)f2bf(u0.w);
    pk[4] = (short)f2bf(u1.x); pk[5] = (short)f2bf(u1.y);
    pk[6] = (short)f2bf(u1.z); pk[7] = (short)f2bf(u1.w);
    *(s16x8*)&A[row * 256 + ((cc ^ (row & 7)) * 8)] = pk;
  }
  __syncthreads();

  f32x4 acc[2][4];

#define DO_GEMM(WT) do {                                                          \
    _Pragma("unroll") for (int rb = 0; rb < 2; ++rb)                              \
      _Pragma("unroll") for (int cb = 0; cb < 4; ++cb)                            \
        acc[rb][cb] = (f32x4){0.f, 0.f, 0.f, 0.f};                                \
    _Pragma("unroll") for (int ks = 0; ks < 8; ++ks) {                            \
      s16x8 af[2]; s16x8 bfr[4];                                                  \
      _Pragma("unroll") for (int rb = 0; rb < 2; ++rb) {                          \
        int row = rb * 16 + c; int kc = ks * 4 + g;                               \
        af[rb] = *(const s16x8*)&A[row * 256 + ((kc ^ (row & 7)) * 8)];           \
      }                                                                           \
      _Pragma("unroll") for (int cb = 0; cb < 4; ++cb) {                          \
        int col = w * 64 + cb * 16 + c;                                           \
        bfr[cb] = *(const s16x8*)&(WT)[col * 256 + ks * 32 + g * 8];              \
      }                                                                           \
      _Pragma("unroll") for (int rb = 0; rb < 2; ++rb)                            \
        _Pragma("unroll") for (int cb = 0; cb < 4; ++cb)                          \
          acc[rb][cb] = __builtin_amdgcn_mfma_f32_16x16x32_bf16(                  \
              af[rb], bfr[cb], acc[rb][cb], 0, 0, 0);                             \
    } } while (0)

  float ebias[4], kbias[4], gg[4], bb[4];
  int cols[4];
#pragma unroll
  for (int cb = 0; cb < 4; ++cb) {
    int col = w * 64 + cb * 16 + c;
    cols[cb] = col;
    ebias[cb] = eeg_b[col]; kbias[cb] = k_b[col];
    gg[cb] = lnk_g[col]; bb[cb] = lnk_b[col];
  }

  // ---- GEMM1: eeg projection ----
  DO_GEMM(wt_eeg);

  // ---- LN stats ----
  {
    float ps[2][4], pq[2][4];
#pragma unroll
    for (int rb = 0; rb < 2; ++rb)
#pragma unroll
      for (int r = 0; r < 4; ++r) {
        float s = 0.f, q2 = 0.f;
#pragma unroll
        for (int cb = 0; cb < 4; ++cb) {
          float v = acc[rb][cb][r] + ebias[cb];
          s += v; q2 += v * v;
        }
        ps[rb][r] = s; pq[rb][r] = q2;
      }
#pragma unroll
    for (int m = 1; m < 16; m <<= 1)
#pragma unroll
      for (int rb = 0; rb < 2; ++rb)
#pragma unroll
        for (int r = 0; r < 4; ++r) {
          ps[rb][r] += __shfl_xor(ps[rb][r], m, 64);
          pq[rb][r] += __shfl_xor(pq[rb][r], m, 64);
        }
    // lane c in [0,8) selects (rb,r)=(c>>2, c&3) statically
    float outS = 0.f, outQ = 0.f;
#pragma unroll
    for (int rb = 0; rb < 2; ++rb)
#pragma unroll
      for (int r = 0; r < 4; ++r)
        if (c == rb * 4 + r) { outS = ps[rb][r]; outQ = pq[rb][r]; }
    if (c < 8) {
      int row = (c >> 2) * 16 + g * 4 + (c & 3);
      PSQH[row * 9 + w * 2 + 0] = outS;
      PSQH[row * 9 + w * 2 + 1] = outQ;
    }
  }
  __syncthreads();
  if (tid < 32) {
    float s = PSQH[tid * 9 + 0] + PSQH[tid * 9 + 2] + PSQH[tid * 9 + 4] + PSQH[tid * 9 + 6];
    float q2 = PSQH[tid * 9 + 1] + PSQH[tid * 9 + 3] + PSQH[tid * 9 + 5] + PSQH[tid * 9 + 7];
    float mean = s * (1.f / 256.f);
    float var = q2 * (1.f / 256.f) - mean * mean;
    ST[tid] = make_float2(mean, rsqrtf(var + 1e-5f));
  }
  __syncthreads();

  // ---- LN apply -> A (swizzled); stage qhat into PSQH (LN partials dead) ----
  PSQH[tid] = qhat[(size_t)b * 512 + tid];
  PSQH[256 + tid] = qhat[(size_t)b * 512 + 256 + tid];
#pragma unroll
  for (int rb = 0; rb < 2; ++rb)
#pragma unroll
    for (int r = 0; r < 4; ++r) {
      int row = rb * 16 + g * 4 + r;
      float2 st = ST[row];
#pragma unroll
      for (int cb = 0; cb < 4; ++cb) {
        float v = (acc[rb][cb][r] + ebias[cb] - st.x) * st.y * gg[cb] + bb[cb];
        A[row * 256 + (cols[cb] ^ ((row & 7) * 8))] = f2bf(v);
      }
    }
  __syncthreads();

  // ---- X' dump to xp (natural layout, coalesced b128) ----
#pragma unroll
  for (int i = 0; i < 4; ++i) {
    int e = i * 256 + tid;
    int row = e >> 5, u = e & 31;
    s16x8 v = *(const s16x8*)&A[row * 256 + ((u ^ (row & 7)) * 8)];
    *(s16x8*)&xp[(size_t)(r0 + row) * 256 + u * 8] = v;
  }

  // ---- GEMM2: K projection ----
  DO_GEMM(wt_k);
  __syncthreads();   // all A reads (GEMM2 + dump) done

  // ---- K epilogue: bias -> bf16 -> A (swizzled); RoPE deferred to score phase ----
#pragma unroll
  for (int rb = 0; rb < 2; ++rb)
#pragma unroll
    for (int r = 0; r < 4; ++r) {
      int row = rb * 16 + g * 4 + r;
#pragma unroll
      for (int cb = 0; cb < 4; ++cb)
        A[row * 256 + (cols[cb] ^ ((row & 7) * 8))] = f2bf(acc[rb][cb][r] + kbias[cb]);
    }
  __syncthreads();

  // ---- score phase: 256 cells = 32 rows x 8 heads, 1/thread; RoPE on the fly ----
  {
    int h = tid >> 5, row = tid & 31;
    const float2* tgp = trig + (size_t)(n0 + row) * 16;
    float ssq = 0.f, d0 = 0.f, d1 = 0.f;
#pragma unroll
    for (int j = 0; j < 4; ++j) {
      s16x8 kvv = *(const s16x8*)&A[row * 256 + (((h * 4 + j) ^ (row & 7)) * 8)];
      float2 t0 = tgp[j * 4 + 0], t1 = tgp[j * 4 + 1], t2 = tgp[j * 4 + 2], t3 = tgp[j * 4 + 3];
      float2 tg4[4] = {t0, t1, t2, t3};
#pragma unroll
      for (int t = 0; t < 4; ++t) {
        float e0 = bf2f((unsigned short)kvv[2 * t]);
        float e1 = bf2f((unsigned short)kvv[2 * t + 1]);
        float2 cs = tg4[t];
        float rv0 = e0 * cs.x - e1 * cs.y;
        float rv1 = fmaf(e1, cs.x, e0 * cs.y);
        int col = h * 32 + j * 8 + 2 * t;
        ssq = fmaf(rv0, rv0, fmaf(rv1, rv1, ssq));
        d0 = fmaf(rv0, PSQH[col], fmaf(rv1, PSQH[col + 1], d0));
        d1 = fmaf(rv0, PSQH[256 + col], fmaf(rv1, PSQH[256 + col + 1], d1));
      }
    }
    float is = 0.17677669529663687f / fmaxf(sqrtf(ssq), 1e-12f);
    scores[(size_t)((b * 8 + h) * 2 + 0) * 4096 + n0 + row] = d0 * is;
    scores[(size_t)((b * 8 + h) * 2 + 1) * 4096 + n0 + row] = d1 * is;
  }
#undef DO_GEMM
}

// ---------------- s1: score stats -> tanh rescale -> softmax -> weights w ----------------
__global__ __launch_bounds__(256) void wgt_kernel(
    const float* __restrict__ scores, float* __restrict__ wbuf) {
  int b = blockIdx.x >> 3, h = blockIdx.x & 7;
  const float* s0p = scores + (size_t)((b * 8 + h) * 2 + 0) * 4096;
  const float* s1p = scores + (size_t)((b * 8 + h) * 2 + 1) * 4096;
  float sa[16], sb[16];
  float a1 = 0.f, a2 = 0.f, b1 = 0.f, b2 = 0.f;
#pragma unroll
  for (int i = 0; i < 16; ++i) {
    int k = i * 256 + TID;
    sa[i] = s0p[k]; sb[i] = s1p[k];
    a1 += sa[i]; a2 += sa[i] * sa[i];
    b1 += sb[i]; b2 += sb[i] * sb[i];
  }
  __shared__ float red[16];
  int w = TID >> 6;
#pragma unroll
  for (int m = 1; m < 64; m <<= 1) {
    a1 += __shfl_xor(a1, m, 64); a2 += __shfl_xor(a2, m, 64);
    b1 += __shfl_xor(b1, m, 64); b2 += __shfl_xor(b2, m, 64);
  }
  if ((TID & 63) == 0) { red[w * 4] = a1; red[w * 4 + 1] = a2; red[w * 4 + 2] = b1; red[w * 4 + 3] = b2; }
  __syncthreads();
  a1 = red[0] + red[4] + red[8] + red[12];
  a2 = red[1] + red[5] + red[9] + red[13];
  b1 = red[2] + red[6] + red[10] + red[14];
  b2 = red[3] + red[7] + red[11] + red[15];
  float va = (a2 - a1 * a1 * (1.f / 4096.f)) * (1.f / 4095.f);   // ddof=1
  float vb = (b2 - b1 * b1 * (1.f / 4096.f)) * (1.f / 4095.f);
  float sga = fmaxf(sqrtf(fmaxf(va, 0.f)), 1e-3f);
  float sgb = fmaxf(sqrtf(fmaxf(vb, 0.f)), 1e-3f);
  float ia = 0.5f / sga, ib = 0.5f / sgb;
  float fa = 5.f * sga, fb = 5.f * sgb;
  float ea = 0.f, eb = 0.f;
#pragma unroll
  for (int i = 0; i < 16; ++i) {
    sa[i] = __expf(tanhf(sa[i] * ia) * fa);    // |arg| <= 5*sigma: no max-sub needed
    sb[i] = __expf(tanhf(sb[i] * ib) * fb);
    ea += sa[i]; eb += sb[i];
  }
#pragma unroll
  for (int m = 1; m < 64; m <<= 1) { ea += __shfl_xor(ea, m, 64); eb += __shfl_xor(eb, m, 64); }
  __syncthreads();
  if ((TID & 63) == 0) { red[w * 2] = ea; red[w * 2 + 1] = eb; }
  __syncthreads();
  ea = red[0] + red[2] + red[4] + red[6];
  eb = red[1] + red[3] + red[5] + red[7];
  float iea = 1.f / ea, ieb = 1.f / eb;   // denom (1+1e-8) == 1.0f in fp32
  float* w0 = wbuf + ((size_t)(b * 16) + h * 2 + 0) * 4096;
  float* w1 = w0 + 4096;
#pragma unroll
  for (int i = 0; i < 16; ++i) {
    int k = i * 256 + TID;
    w0[k] = fmaf(sa[i], iea, 1e-4f);
    w1[k] = fmaf(sb[i], ieb, 1e-4f);
  }
}

// ---------------- s2: y partials = sum_n w[n] * X'[n,:] over 128-row slabs ----------------
__global__ __launch_bounds__(256) void ysum_kernel(
    const unsigned short* __restrict__ xp, const float* __restrict__ wbuf,
    float* __restrict__ ypart) {
  int b = blockIdx.x >> 5, slab = blockIdx.x & 31;
  int h = TID >> 5, cg = TID & 31;                 // 8 heads x 32 col-groups
  const unsigned short* xb = xp + ((size_t)b * 4096 + slab * 128) * 256 + cg * 8;
  const float* w0 = wbuf + ((size_t)(b * 16) + h * 2 + 0) * 4096 + slab * 128;
  const float* w1 = w0 + 4096;
  float y0[8], y1[8];
#pragma unroll
  for (int t = 0; t < 8; ++t) { y0[t] = 0.f; y1[t] = 0.f; }
#pragma unroll 4
  for (int r = 0; r < 128; ++r) {
    s16x8 xv = *(const s16x8*)(xb + (size_t)r * 256);
    float wa = w0[r], wc = w1[r];
#pragma unroll
    for (int t = 0; t < 8; ++t) {
      float xf = bf2f((unsigned short)xv[t]);
      y0[t] = fmaf(wa, xf, y0[t]);
      y1[t] = fmaf(wc, xf, y1[t]);
    }
  }
  float* yp = ypart + (((size_t)(b * 32 + slab) * 16) + h * 2) * 256 + cg * 8;
  *(float4*)&yp[0] = (float4){y0[0], y0[1], y0[2], y0[3]};
  *(float4*)&yp[4] = (float4){y0[4], y0[5], y0[6], y0[7]};
  *(float4*)&yp[256] = (float4){y1[0], y1[1], y1[2], y1[3]};
  *(float4*)&yp[260] = (float4){y1[4], y1[5], y1[6], y1[7]};
}

// ---------------- s3: reduce y, @ v_w + 1.4096*v_b -> attn_out, pooled, logits ----------------
__global__ __launch_bounds__(256) void finish_kernel(
    const float* __restrict__ ypart, const float* __restrict__ v_w,
    const float* __restrict__ v_b, const float* __restrict__ fc_w,
    const float* __restrict__ fc_b, float* __restrict__ out_attn,
    float* __restrict__ out_pooled, float* __restrict__ out_logits) {
  int b = blockIdx.x;
  __shared__ float Y[16][256];
  __shared__ float ATT[2][256];
  __shared__ float P[256];
  for (int idx = TID; idx < 4096; idx += 256) {
    int hq = idx >> 8, cc = idx & 255;
    float s = 0.f;
#pragma unroll 8
    for (int sl = 0; sl < 32; ++sl)
      s += ypart[(((size_t)(b * 32 + sl) * 16) + hq) * 256 + cc];
    Y[hq][cc] = s;
  }
  __syncthreads();
#pragma unroll
  for (int o = TID; o < 512; o += 256) {
    int q = o >> 8, dout = o & 255;
    int hq = (dout >> 5) * 2 + q;
    float acc = 1.4096f * v_b[dout];     // sum(w) = 1 + 4096e-4 exactly
#pragma unroll 8
    for (int c2 = 0; c2 < 256; ++c2)
      acc = fmaf(Y[hq][c2], v_w[c2 * 256 + dout], acc);
    out_attn[(b * 2 + q) * 256 + dout] = acc;
    ATT[q][dout] = acc;
  }
  __syncthreads();
  float p = 0.5f * (ATT[0][TID] + ATT[1][TID]);
  out_pooled[b * 256 + TID] = p;
  P[TID] = p;
  __syncthreads();
  if (TID < 40) {
    float acc = fc_b[TID];
#pragma unroll 8
    for (int i = 0; i < 256; ++i) acc = fmaf(P[i], fc_w[i * 40 + TID], acc);
    out_logits[b * 40 + TID] = acc;
  }
}

extern "C" void kernel_launch(void* const* d_in, const int* in_sizes, int n_in,
                              void* d_out, int out_size, void* d_ws, size_t ws_size,
                              hipStream_t stream) {
  (void)in_sizes; (void)n_in; (void)out_size; (void)ws_size;
  const float* eeg_feat  = (const float*)d_in[0];
  const float* stim_feat = (const float*)d_in[1];
  const float* temp_feat = (const float*)d_in[2];
  const float* eeg_w = (const float*)d_in[3];
  const float* eeg_b = (const float*)d_in[4];
  const float* stim_w = (const float*)d_in[5];
  const float* stim_b = (const float*)d_in[6];
  const float* temp_w = (const float*)d_in[7];
  const float* temp_b = (const float*)d_in[8];
  const float* q_w = (const float*)d_in[9];
  const float* q_b = (const float*)d_in[10];
  const float* k_w = (const float*)d_in[11];
  const float* k_b = (const float*)d_in[12];
  const float* v_w = (const float*)d_in[13];
  const float* v_b = (const float*)d_in[14];
  const float* fc_w = (const float*)d_in[15];
  const float* fc_b = (const float*)d_in[16];
  const float* lnq_g = (const float*)d_in[17];
  const float* lnq_b = (const float*)d_in[18];
  const float* lnk_g = (const float*)d_in[19];
  const float* lnk_b = (const float*)d_in[20];

  char* ws = (char*)d_ws;
  unsigned short* wt  = (unsigned short*)(ws + 0);          // 256 KB (eeg^T, k^T bf16)
  float2* trig        = (float2*)(ws + 393216);             // 512 KB
  float* qhat         = (float*)(ws + 917504);              // 64 KB
  float* scores       = (float*)(ws + 1048576);             // 8 MB
  float* wbuf         = (float*)(ws + 9437184);             // 8 MB  (attn weights fp32)
  unsigned short* xp  = (unsigned short*)(ws + 17825792);   // 64 MB (LN'd X bf16, natural layout)
  float* ypart        = (float*)(ws + 84934656);            // 16 MB (y partials)

  float* out = (float*)d_out;
  float* out_logits = out;                 // 32*40
  float* out_pooled = out + 1280;          // 32*256
  float* out_attn   = out + 9472;          // 32*2*256
  float* out_query  = out + 25856;         // 32*2*256

  prep_kernel<<<768, 256, 0, stream>>>(eeg_w, k_w, wt, trig);
  q_kernel<<<64, 256, 0, stream>>>(stim_feat, temp_feat, stim_w, stim_b,
                                   temp_w, temp_b, q_w, q_b, lnq_g, lnq_b,
                                   out_query, qhat);
  main_kernel<<<4096, 256, 0, stream>>>(eeg_feat, eeg_b, k_b, lnk_g, lnk_b,
                                        wt, wt + 65536, trig, qhat, scores, xp);
  wgt_kernel<<<256, 256, 0, stream>>>(scores, wbuf);
  ysum_kernel<<<1024, 256, 0, stream>>>(xp, wbuf, ypart);
  finish_kernel<<<32, 256, 0, stream>>>(ypart, v_w, v_b, fc_w, fc_b,
                                        out_attn, out_pooled, out_logits);
}

// Round 6
// 238.262 us; speedup vs baseline: 1.8393x; 1.1726x over previous
//
#include <hip/hip_runtime.h>
#include <hip/hip_bf16.h>
#include <math.h>

#define TID ((int)threadIdx.x)

typedef float f32x4 __attribute__((ext_vector_type(4)));
typedef short s16x8 __attribute__((ext_vector_type(8)));

__device__ __forceinline__ unsigned short f2bf(float f) {
  union { float f; unsigned u; } v; v.f = f;
  unsigned r = v.u + 0x7FFFu + ((v.u >> 16) & 1u);
  return (unsigned short)(r >> 16);
}
__device__ __forceinline__ float bf2f(unsigned short h) {
  union { unsigned u; float f; } v; v.u = ((unsigned)h) << 16;
  return v.f;
}

// ---------------- prep: eeg_w/k_w transpose->bf16 + RoPE trig table ----------------
__global__ void prep_kernel(const float* __restrict__ eeg_w,
                            const float* __restrict__ k_w,
                            unsigned short* __restrict__ wt,
                            float2* __restrict__ trig) {
  int gid = blockIdx.x * 256 + TID;            // grid = 768*256 = 196608 exactly
  if (gid < 2 * 65536) {
    int m = gid >> 16, e = gid & 65535;
    int i = e >> 8, j = e & 255;
    const float* W = (m == 0) ? eeg_w : k_w;
    wt[m * 65536 + j * 256 + i] = f2bf(W[i * 256 + j]);
  } else {
    int e = gid - 2 * 65536;                   // < 65536
    int n = e >> 4, p = e & 15;
    float inv = exp2f(-(float)p * 0.8304820237218406f);  // 10000^(-p/16)
    float a = (float)n * inv;
    trig[e] = make_float2(cosf(a), sinf(a));
  }
}

// ---------------- query path (unchanged, verified) ----------------
__global__ __launch_bounds__(256) void q_kernel(
    const float* __restrict__ stim_feat, const float* __restrict__ temp_feat,
    const float* __restrict__ stim_w, const float* __restrict__ stim_b,
    const float* __restrict__ temp_w, const float* __restrict__ temp_b,
    const float* __restrict__ q_w, const float* __restrict__ q_b,
    const float* __restrict__ lnq_g, const float* __restrict__ lnq_b,
    float* __restrict__ out_query, float* __restrict__ qhat) {
  int b = blockIdx.x >> 1, q = blockIdx.x & 1;
  __shared__ float f[256];
  __shared__ float red[8];
  const float* feat = (q ? temp_feat : stim_feat) + b * 256;
  const float* W = q ? temp_w : stim_w;
  const float* bias = q ? temp_b : stim_b;
  f[TID] = feat[TID];
  __syncthreads();
  float acc = bias[TID];
#pragma unroll 8
  for (int i = 0; i < 256; ++i) acc = fmaf(f[i], W[i * 256 + TID], acc);
  float s1 = acc, s2 = acc * acc;
#pragma unroll
  for (int m = 1; m < 64; m <<= 1) { s1 += __shfl_xor(s1, m, 64); s2 += __shfl_xor(s2, m, 64); }
  if ((TID & 63) == 0) { red[TID >> 6] = s1; red[4 + (TID >> 6)] = s2; }
  __syncthreads();
  s1 = red[0] + red[1] + red[2] + red[3];
  s2 = red[4] + red[5] + red[6] + red[7];
  float mean = s1 * (1.f / 256.f);
  float var = s2 * (1.f / 256.f) - mean * mean;
  float rstd = rsqrtf(var + 1e-5f);
  float qln = (acc - mean) * rstd * lnq_g[TID] + lnq_b[TID];
  out_query[(b * 2 + q) * 256 + TID] = qln;
  __syncthreads();
  f[TID] = qln;
  __syncthreads();
  float a2 = q_b[TID];
#pragma unroll 8
  for (int i = 0; i < 256; ++i) a2 = fmaf(f[i], q_w[i * 256 + TID], a2);
  __syncthreads();
  f[TID] = a2;
  __syncthreads();
  float partner = f[TID ^ 1];
  int p = (TID >> 1) & 15;
  float inv = exp2f(-(float)p * 0.8304820237218406f);
  float ang = (float)q * inv;
  float cc_ = cosf(ang), ss_ = sinf(ang);
  float r = (TID & 1) ? fmaf(a2, cc_, partner * ss_) : fmaf(a2, cc_, -partner * ss_);
  float sq = r * r;
#pragma unroll
  for (int m = 1; m < 32; m <<= 1) sq += __shfl_xor(sq, m, 32);
  float rs = 1.f / fmaxf(sqrtf(sq), 1e-12f);
  qhat[(b * 2 + q) * 256 + TID] = r * rs;
}

// ---------------- k1: weight-stationary eeg proj + LN -> xp (swizzle-encoded layout) ----------------
// 512 blocks x 8 tiles of 32 rows. B fragments live in VGPRs for the whole kernel.
__global__ __launch_bounds__(256) void eeg_ln_kernel(
    const float* __restrict__ x,
    const float* __restrict__ eeg_b,
    const float* __restrict__ lnk_g,
    const float* __restrict__ lnk_b,
    const unsigned short* __restrict__ wt_eeg,
    unsigned short* __restrict__ xp) {

  __shared__ __align__(16) unsigned short A0[32 * 256];   // 16KB dbuf
  __shared__ __align__(16) unsigned short A1[32 * 256];   // 16KB
  __shared__ float PS[32 * 9];
  __shared__ float2 ST[32];

  const int tid = TID;
  const int w = tid >> 6, l = tid & 63, g = l >> 4, c = l & 15;
  const size_t base = (size_t)blockIdx.x * 65536;   // 256 rows * 256 cols

  // ---- weight-stationary B fragments: 64 cols/wave, 128 VGPR ----
  s16x8 bfr[8][4];
#pragma unroll
  for (int ks = 0; ks < 8; ++ks)
#pragma unroll
    for (int cb = 0; cb < 4; ++cb)
      bfr[ks][cb] = *(const s16x8*)&wt_eeg[(size_t)(w * 64 + cb * 16 + c) * 256 + ks * 32 + g * 8];

  float ebias[4], gg[4], bb[4];
  int cols[4];
#pragma unroll
  for (int cb = 0; cb < 4; ++cb) {
    int col = w * 64 + cb * 16 + c;
    cols[cb] = col;
    ebias[cb] = eeg_b[col]; gg[cb] = lnk_g[col]; bb[cb] = lnk_b[col];
  }

  float4 sxa[4], sxb[4];
  {
    const float* xt = x + base;
#pragma unroll
    for (int i = 0; i < 4; ++i) {
      int ch = i * 256 + tid, row = ch >> 5, cc = ch & 31;
      const float4* gp = (const float4*)(xt + row * 256 + cc * 8);
      sxa[i] = gp[0]; sxb[i] = gp[1];
    }
  }

#pragma unroll
  for (int t = 0; t < 8; ++t) {
    unsigned short* Ab = (t & 1) ? A1 : A0;
    // ---- staged regs -> LDS (fp32->bf16, swizzled) ----
#pragma unroll
    for (int i = 0; i < 4; ++i) {
      int ch = i * 256 + tid, row = ch >> 5, cc = ch & 31;
      s16x8 pk;
      pk[0] = (short)f2bf(sxa[i].x); pk[1] = (short)f2bf(sxa[i].y);
      pk[2] = (short)f2bf(sxa[i].z); pk[3] = (short)f2bf(sxa[i].w);
      pk[4] = (short)f2bf(sxb[i].x); pk[5] = (short)f2bf(sxb[i].y);
      pk[6] = (short)f2bf(sxb[i].z); pk[7] = (short)f2bf(sxb[i].w);
      *(s16x8*)&Ab[row * 256 + ((cc ^ (row & 7)) * 8)] = pk;
    }
    __syncthreads();
    // ---- prefetch next tile (in flight across this tile's compute) ----
    if (t < 7) {
      const float* xt = x + base + (size_t)(t + 1) * 8192;
#pragma unroll
      for (int i = 0; i < 4; ++i) {
        int ch = i * 256 + tid, row = ch >> 5, cc = ch & 31;
        const float4* gp = (const float4*)(xt + row * 256 + cc * 8);
        sxa[i] = gp[0]; sxb[i] = gp[1];
      }
    }
    // ---- GEMM (LDS + MFMA only, B in regs) ----
    f32x4 acc[2][4];
#pragma unroll
    for (int rb = 0; rb < 2; ++rb)
#pragma unroll
      for (int cb = 0; cb < 4; ++cb) acc[rb][cb] = (f32x4){0.f, 0.f, 0.f, 0.f};
#pragma unroll
    for (int ks = 0; ks < 8; ++ks) {
      s16x8 af[2];
#pragma unroll
      for (int rb = 0; rb < 2; ++rb) {
        int row = rb * 16 + c; int kc = ks * 4 + g;
        af[rb] = *(const s16x8*)&Ab[row * 256 + ((kc ^ (row & 7)) * 8)];
      }
#pragma unroll
      for (int rb = 0; rb < 2; ++rb)
#pragma unroll
        for (int cb = 0; cb < 4; ++cb)
          acc[rb][cb] = __builtin_amdgcn_mfma_f32_16x16x32_bf16(af[rb], bfr[ks][cb], acc[rb][cb], 0, 0, 0);
    }
    // ---- LN stats ----
    {
      float ps[2][4], pq[2][4];
#pragma unroll
      for (int rb = 0; rb < 2; ++rb)
#pragma unroll
        for (int r = 0; r < 4; ++r) {
          float s = 0.f, q2 = 0.f;
#pragma unroll
          for (int cb = 0; cb < 4; ++cb) {
            float v = acc[rb][cb][r] + ebias[cb];
            s += v; q2 += v * v;
          }
          ps[rb][r] = s; pq[rb][r] = q2;
        }
#pragma unroll
      for (int m = 1; m < 16; m <<= 1)
#pragma unroll
        for (int rb = 0; rb < 2; ++rb)
#pragma unroll
          for (int r = 0; r < 4; ++r) {
            ps[rb][r] += __shfl_xor(ps[rb][r], m, 64);
            pq[rb][r] += __shfl_xor(pq[rb][r], m, 64);
          }
      float outS = 0.f, outQ = 0.f;
#pragma unroll
      for (int rb = 0; rb < 2; ++rb)
#pragma unroll
        for (int r = 0; r < 4; ++r)
          if (c == rb * 4 + r) { outS = ps[rb][r]; outQ = pq[rb][r]; }
      if (c < 8) {
        int row = (c >> 2) * 16 + g * 4 + (c & 3);
        PS[row * 9 + w * 2 + 0] = outS;
        PS[row * 9 + w * 2 + 1] = outQ;
      }
    }
    __syncthreads();
    if (tid < 32) {
      float s = PS[tid * 9 + 0] + PS[tid * 9 + 2] + PS[tid * 9 + 4] + PS[tid * 9 + 6];
      float q2 = PS[tid * 9 + 1] + PS[tid * 9 + 3] + PS[tid * 9 + 5] + PS[tid * 9 + 7];
      float mean = s * (1.f / 256.f);
      float var = q2 * (1.f / 256.f) - mean * mean;
      ST[tid] = make_float2(mean, rsqrtf(var + 1e-5f));
    }
    __syncthreads();
    // ---- LN apply -> Ab (in place, swizzled) ----
#pragma unroll
    for (int rb = 0; rb < 2; ++rb)
#pragma unroll
      for (int r = 0; r < 4; ++r) {
        int row = rb * 16 + g * 4 + r;
        float2 st = ST[row];
#pragma unroll
        for (int cb = 0; cb < 4; ++cb) {
          float v = (acc[rb][cb][r] + ebias[cb] - st.x) * st.y * gg[cb] + bb[cb];
          Ab[row * 256 + (cols[cb] ^ ((row & 7) * 8))] = f2bf(v);
        }
      }
    __syncthreads();
    // ---- dump LINEAR (swizzle stays encoded in xp layout) ----
#pragma unroll
    for (int j = 0; j < 4; ++j) {
      int e = j * 256 + tid;
      *(s16x8*)&xp[base + (size_t)t * 8192 + (size_t)e * 8] = *(const s16x8*)&Ab[e * 8];
    }
  }
}

// ---------------- k2: weight-stationary K proj + deferred-RoPE scores ----------------
__global__ __launch_bounds__(256) void k_score_kernel(
    const unsigned short* __restrict__ xp,
    const float* __restrict__ k_b,
    const unsigned short* __restrict__ wt_k,
    const float2* __restrict__ trig,
    const float* __restrict__ qhat,
    float* __restrict__ scores) {

  __shared__ __align__(16) unsigned short A0[32 * 256];
  __shared__ __align__(16) unsigned short A1[32 * 256];
  __shared__ __align__(16) unsigned short K2[32 * 256];
  __shared__ float QH[512];

  const int tid = TID;
  const int w = tid >> 6, l = tid & 63, g = l >> 4, c = l & 15;
  const size_t base = (size_t)blockIdx.x * 65536;
  const int r0blk = blockIdx.x * 256;
  const int b = r0blk >> 12;
  const int n0blk = r0blk & 4095;

  s16x8 bfr[8][4];
#pragma unroll
  for (int ks = 0; ks < 8; ++ks)
#pragma unroll
    for (int cb = 0; cb < 4; ++cb)
      bfr[ks][cb] = *(const s16x8*)&wt_k[(size_t)(w * 64 + cb * 16 + c) * 256 + ks * 32 + g * 8];

  float kbias[4];
  int cols[4];
#pragma unroll
  for (int cb = 0; cb < 4; ++cb) {
    int col = w * 64 + cb * 16 + c;
    cols[cb] = col; kbias[cb] = k_b[col];
  }
  QH[tid] = qhat[(size_t)b * 512 + tid];
  QH[256 + tid] = qhat[(size_t)b * 512 + 256 + tid];

  s16x8 sx[4];
#pragma unroll
  for (int i = 0; i < 4; ++i)
    sx[i] = *(const s16x8*)&xp[base + (size_t)(i * 256 + tid) * 8];

#pragma unroll
  for (int t = 0; t < 8; ++t) {
    unsigned short* Ab = (t & 1) ? A1 : A0;
#pragma unroll
    for (int i = 0; i < 4; ++i)
      *(s16x8*)&Ab[(size_t)(i * 256 + tid) * 8] = sx[i];
    __syncthreads();   // staging+QH visible; all waves past score(t-1) so K2 free
    if (t < 7) {
#pragma unroll
      for (int i = 0; i < 4; ++i)
        sx[i] = *(const s16x8*)&xp[base + (size_t)(t + 1) * 8192 + (size_t)(i * 256 + tid) * 8];
    }
    f32x4 acc[2][4];
#pragma unroll
    for (int rb = 0; rb < 2; ++rb)
#pragma unroll
      for (int cb = 0; cb < 4; ++cb) acc[rb][cb] = (f32x4){0.f, 0.f, 0.f, 0.f};
#pragma unroll
    for (int ks = 0; ks < 8; ++ks) {
      s16x8 af[2];
#pragma unroll
      for (int rb = 0; rb < 2; ++rb) {
        int row = rb * 16 + c; int kc = ks * 4 + g;
        af[rb] = *(const s16x8*)&Ab[row * 256 + ((kc ^ (row & 7)) * 8)];
      }
#pragma unroll
      for (int rb = 0; rb < 2; ++rb)
#pragma unroll
        for (int cb = 0; cb < 4; ++cb)
          acc[rb][cb] = __builtin_amdgcn_mfma_f32_16x16x32_bf16(af[rb], bfr[ks][cb], acc[rb][cb], 0, 0, 0);
    }
    // ---- K epilogue: bias -> bf16 -> K2 (swizzled) ----
#pragma unroll
    for (int rb = 0; rb < 2; ++rb)
#pragma unroll
      for (int r = 0; r < 4; ++r) {
        int row = rb * 16 + g * 4 + r;
#pragma unroll
        for (int cb = 0; cb < 4; ++cb)
          K2[row * 256 + (cols[cb] ^ ((row & 7) * 8))] = f2bf(acc[rb][cb][r] + kbias[cb]);
      }
    __syncthreads();   // K2 visible
    // ---- score phase: RoPE on the fly, no cross-lane ----
    {
      int n0 = n0blk + t * 32;
      int h = tid >> 5, row = tid & 31;
      const float2* tgp = trig + (size_t)(n0 + row) * 16;
      float ssq = 0.f, d0 = 0.f, d1 = 0.f;
#pragma unroll
      for (int j = 0; j < 4; ++j) {
        s16x8 kvv = *(const s16x8*)&K2[row * 256 + (((h * 4 + j) ^ (row & 7)) * 8)];
        float2 t0 = tgp[j * 4 + 0], t1 = tgp[j * 4 + 1], t2 = tgp[j * 4 + 2], t3 = tgp[j * 4 + 3];
        float2 tg4[4] = {t0, t1, t2, t3};
#pragma unroll
        for (int u = 0; u < 4; ++u) {
          float e0 = bf2f((unsigned short)kvv[2 * u]);
          float e1 = bf2f((unsigned short)kvv[2 * u + 1]);
          float2 cs = tg4[u];
          float rv0 = e0 * cs.x - e1 * cs.y;
          float rv1 = fmaf(e1, cs.x, e0 * cs.y);
          int col = h * 32 + j * 8 + 2 * u;
          ssq = fmaf(rv0, rv0, fmaf(rv1, rv1, ssq));
          d0 = fmaf(rv0, QH[col], fmaf(rv1, QH[col + 1], d0));
          d1 = fmaf(rv0, QH[256 + col], fmaf(rv1, QH[256 + col + 1], d1));
        }
      }
      float is = 0.17677669529663687f / fmaxf(sqrtf(ssq), 1e-12f);
      scores[(size_t)((b * 8 + h) * 2 + 0) * 4096 + n0 + row] = d0 * is;
      scores[(size_t)((b * 8 + h) * 2 + 1) * 4096 + n0 + row] = d1 * is;
    }
  }
}

// ---------------- s1: score stats -> tanh rescale -> softmax -> weights w ----------------
__global__ __launch_bounds__(256) void wgt_kernel(
    const float* __restrict__ scores, float* __restrict__ wbuf) {
  int b = blockIdx.x >> 3, h = blockIdx.x & 7;
  const float* s0p = scores + (size_t)((b * 8 + h) * 2 + 0) * 4096;
  const float* s1p = scores + (size_t)((b * 8 + h) * 2 + 1) * 4096;
  float sa[16], sb[16];
  float a1 = 0.f, a2 = 0.f, b1 = 0.f, b2 = 0.f;
#pragma unroll
  for (int i = 0; i < 16; ++i) {
    int k = i * 256 + TID;
    sa[i] = s0p[k]; sb[i] = s1p[k];
    a1 += sa[i]; a2 += sa[i] * sa[i];
    b1 += sb[i]; b2 += sb[i] * sb[i];
  }
  __shared__ float red[16];
  int w = TID >> 6;
#pragma unroll
  for (int m = 1; m < 64; m <<= 1) {
    a1 += __shfl_xor(a1, m, 64); a2 += __shfl_xor(a2, m, 64);
    b1 += __shfl_xor(b1, m, 64); b2 += __shfl_xor(b2, m, 64);
  }
  if ((TID & 63) == 0) { red[w * 4] = a1; red[w * 4 + 1] = a2; red[w * 4 + 2] = b1; red[w * 4 + 3] = b2; }
  __syncthreads();
  a1 = red[0] + red[4] + red[8] + red[12];
  a2 = red[1] + red[5] + red[9] + red[13];
  b1 = red[2] + red[6] + red[10] + red[14];
  b2 = red[3] + red[7] + red[11] + red[15];
  float va = (a2 - a1 * a1 * (1.f / 4096.f)) * (1.f / 4095.f);   // ddof=1
  float vb = (b2 - b1 * b1 * (1.f / 4096.f)) * (1.f / 4095.f);
  float sga = fmaxf(sqrtf(fmaxf(va, 0.f)), 1e-3f);
  float sgb = fmaxf(sqrtf(fmaxf(vb, 0.f)), 1e-3f);
  float ia = 0.5f / sga, ib = 0.5f / sgb;
  float fa = 5.f * sga, fb = 5.f * sgb;
  float ea = 0.f, eb = 0.f;
#pragma unroll
  for (int i = 0; i < 16; ++i) {
    sa[i] = __expf(tanhf(sa[i] * ia) * fa);    // |arg| <= 5*sigma: no max-sub needed
    sb[i] = __expf(tanhf(sb[i] * ib) * fb);
    ea += sa[i]; eb += sb[i];
  }
#pragma unroll
  for (int m = 1; m < 64; m <<= 1) { ea += __shfl_xor(ea, m, 64); eb += __shfl_xor(eb, m, 64); }
  __syncthreads();
  if ((TID & 63) == 0) { red[w * 2] = ea; red[w * 2 + 1] = eb; }
  __syncthreads();
  ea = red[0] + red[2] + red[4] + red[6];
  eb = red[1] + red[3] + red[5] + red[7];
  float iea = 1.f / ea, ieb = 1.f / eb;   // denom (1+1e-8) == 1.0f in fp32
  float* w0 = wbuf + ((size_t)(b * 16) + h * 2 + 0) * 4096;
  float* w1 = w0 + 4096;
#pragma unroll
  for (int i = 0; i < 16; ++i) {
    int k = i * 256 + TID;
    w0[k] = fmaf(sa[i], iea, 1e-4f);
    w1[k] = fmaf(sb[i], ieb, 1e-4f);
  }
}

// ---------------- s2: y partials = sum_n w[n] * X'[n,:] (xp is swizzle-encoded) ----------------
__global__ __launch_bounds__(256) void ysum_kernel(
    const unsigned short* __restrict__ xp, const float* __restrict__ wbuf,
    float* __restrict__ ypart) {
  int b = blockIdx.x >> 5, slab = blockIdx.x & 31;
  int h = TID >> 5, cg = TID & 31;                 // 8 heads x 32 col-groups
  const unsigned short* xb = xp + ((size_t)b * 4096 + slab * 128) * 256;
  const float* w0 = wbuf + ((size_t)(b * 16) + h * 2 + 0) * 4096 + slab * 128;
  const float* w1 = w0 + 4096;
  float y0[8], y1[8];
#pragma unroll
  for (int t = 0; t < 8; ++t) { y0[t] = 0.f; y1[t] = 0.f; }
#pragma unroll 4
  for (int r = 0; r < 128; ++r) {
    s16x8 xv = *(const s16x8*)&xb[(size_t)r * 256 + ((cg ^ (r & 7)) * 8)];
    float wa = w0[r], wc = w1[r];
#pragma unroll
    for (int t = 0; t < 8; ++t) {
      float xf = bf2f((unsigned short)xv[t]);
      y0[t] = fmaf(wa, xf, y0[t]);
      y1[t] = fmaf(wc, xf, y1[t]);
    }
  }
  float* yp = ypart + (((size_t)(b * 32 + slab) * 16) + h * 2) * 256 + cg * 8;
  *(float4*)&yp[0] = (float4){y0[0], y0[1], y0[2], y0[3]};
  *(float4*)&yp[4] = (float4){y0[4], y0[5], y0[6], y0[7]};
  *(float4*)&yp[256] = (float4){y1[0], y1[1], y1[2], y1[3]};
  *(float4*)&yp[260] = (float4){y1[4], y1[5], y1[6], y1[7]};
}

// ---------------- s3: reduce y, @ v_w + 1.4096*v_b -> attn_out, pooled, logits ----------------
__global__ __launch_bounds__(256) void finish_kernel(
    const float* __restrict__ ypart, const float* __restrict__ v_w,
    const float* __restrict__ v_b, const float* __restrict__ fc_w,
    const float* __restrict__ fc_b, float* __restrict__ out_attn,
    float* __restrict__ out_pooled, float* __restrict__ out_logits) {
  int b = blockIdx.x;
  __shared__ float Y[16][256];
  __shared__ float ATT[2][256];
  __shared__ float P[256];
  for (int idx = TID; idx < 4096; idx += 256) {
    int hq = idx >> 8, cc = idx & 255;
    float s = 0.f;
#pragma unroll 8
    for (int sl = 0; sl < 32; ++sl)
      s += ypart[(((size_t)(b * 32 + sl) * 16) + hq) * 256 + cc];
    Y[hq][cc] = s;
  }
  __syncthreads();
#pragma unroll
  for (int o = TID; o < 512; o += 256) {
    int q = o >> 8, dout = o & 255;
    int hq = (dout >> 5) * 2 + q;
    float acc = 1.4096f * v_b[dout];     // sum(w) = 1 + 4096e-4 exactly
#pragma unroll 8
    for (int c2 = 0; c2 < 256; ++c2)
      acc = fmaf(Y[hq][c2], v_w[c2 * 256 + dout], acc);
    out_attn[(b * 2 + q) * 256 + dout] = acc;
    ATT[q][dout] = acc;
  }
  __syncthreads();
  float p = 0.5f * (ATT[0][TID] + ATT[1][TID]);
  out_pooled[b * 256 + TID] = p;
  P[TID] = p;
  __syncthreads();
  if (TID < 40) {
    float acc = fc_b[TID];
#pragma unroll 8
    for (int i = 0; i < 256; ++i) acc = fmaf(P[i], fc_w[i * 40 + TID], acc);
    out_logits[b * 40 + TID] = acc;
  }
}

extern "C" void kernel_launch(void* const* d_in, const int* in_sizes, int n_in,
                              void* d_out, int out_size, void* d_ws, size_t ws_size,
                              hipStream_t stream) {
  (void)in_sizes; (void)n_in; (void)out_size; (void)ws_size;
  const float* eeg_feat  = (const float*)d_in[0];
  const float* stim_feat = (const float*)d_in[1];
  const float* temp_feat = (const float*)d_in[2];
  const float* eeg_w = (const float*)d_in[3];
  const float* eeg_b = (const float*)d_in[4];
  const float* stim_w = (const float*)d_in[5];
  const float* stim_b = (const float*)d_in[6];
  const float* temp_w = (const float*)d_in[7];
  const float* temp_b = (const float*)d_in[8];
  const float* q_w = (const float*)d_in[9];
  const float* q_b = (const float*)d_in[10];
  const float* k_w = (const float*)d_in[11];
  const float* k_b = (const float*)d_in[12];
  const float* v_w = (const float*)d_in[13];
  const float* v_b = (const float*)d_in[14];
  const float* fc_w = (const float*)d_in[15];
  const float* fc_b = (const float*)d_in[16];
  const float* lnq_g = (const float*)d_in[17];
  const float* lnq_b = (const float*)d_in[18];
  const float* lnk_g = (const float*)d_in[19];
  const float* lnk_b = (const float*)d_in[20];

  char* ws = (char*)d_ws;
  unsigned short* wt  = (unsigned short*)(ws + 0);          // 256 KB (eeg^T, k^T bf16)
  float2* trig        = (float2*)(ws + 393216);             // 512 KB
  float* qhat         = (float*)(ws + 917504);              // 64 KB
  float* scores       = (float*)(ws + 1048576);             // 8 MB
  float* wbuf         = (float*)(ws + 9437184);             // 8 MB  (attn weights fp32)
  unsigned short* xp  = (unsigned short*)(ws + 17825792);   // 64 MB (LN'd X bf16, swizzle-encoded)
  float* ypart        = (float*)(ws + 84934656);            // 16 MB (y partials)

  float* out = (float*)d_out;
  float* out_logits = out;                 // 32*40
  float* out_pooled = out + 1280;          // 32*256
  float* out_attn   = out + 9472;          // 32*2*256
  float* out_query  = out + 25856;         // 32*2*256

  prep_kernel<<<768, 256, 0, stream>>>(eeg_w, k_w, wt, trig);
  q_kernel<<<64, 256, 0, stream>>>(stim_feat, temp_feat, stim_w, stim_b,
                                   temp_w, temp_b, q_w, q_b, lnq_g, lnq_b,
                                   out_query, qhat);
  eeg_ln_kernel<<<512, 256, 0, stream>>>(eeg_feat, eeg_b, lnk_g, lnk_b, wt, xp);
  k_score_kernel<<<512, 256, 0, stream>>>(xp, k_b, wt + 65536, trig, qhat, scores);
  wgt_kernel<<<256, 256, 0, stream>>>(scores, wbuf);
  ysum_kernel<<<1024, 256, 0, stream>>>(xp, wbuf, ypart);
  finish_kernel<<<32, 256, 0, stream>>>(ypart, v_w, v_b, fc_w, fc_b,
                                        out_attn, out_pooled, out_logits);
}